// Round 6
// baseline (387.433 us; speedup 1.0000x reference)
//
#include <hip/hip_runtime.h>
#include <hip/hip_bf16.h>

#define CIN 256
#define COUT 64
#define WPAD 264       // padded K stride for transposed W in LDS
#define BSHIFT 7       // nodes per bucket = 128
#define NPB 128        // nodes per bucket
#define NWG 256        // workgroups for binning passes
#define SENT ((int)0x80000000u)  // sentinel pad word in packed[]
#define SEGCAP 12288   // LDS staging capacity for one bucket segment (ints, 48KB)

typedef __attribute__((ext_vector_type(8))) short short8;
typedef __attribute__((ext_vector_type(4))) float floatx4;

static __device__ __forceinline__ unsigned int fbits(float f) {
    return __builtin_bit_cast(unsigned int, f);
}
static __device__ __forceinline__ float bbits(unsigned int u) {
    return __builtin_bit_cast(float, u);
}
// RTN fp32->bf16 (gemm epilogue only)
static __device__ __forceinline__ unsigned short f2bf(float f) {
    unsigned u = fbits(f);
    return (unsigned short)((u + 0x7FFFu + ((u >> 16) & 1u)) >> 16);
}

// truncation-split of 8 fp32 into bf16 hi/lo short8 fragments (v_perm packing).
union U8 { short8 s; unsigned int u[4]; };
static __device__ __forceinline__ void split8(floatx4 a0, floatx4 a1,
                                              short8& hi, short8& lo) {
    float f[8] = {a0[0], a0[1], a0[2], a0[3], a1[0], a1[1], a1[2], a1[3]};
    U8 H, L;
#pragma unroll
    for (int j = 0; j < 4; ++j) {
        unsigned u0 = fbits(f[2 * j]);
        unsigned u1 = fbits(f[2 * j + 1]);
        H.u[j] = __builtin_amdgcn_perm(u1, u0, 0x07060302u);
        float r0 = f[2 * j] - bbits(u0 & 0xFFFF0000u);
        float r1 = f[2 * j + 1] - bbits(u1 & 0xFFFF0000u);
        L.u[j] = __builtin_amdgcn_perm(fbits(r1), fbits(r0), 0x07060302u);
    }
    hi = H.s;
    lo = L.s;
}

// ---------------- K1: per-workgroup bucket histogram ----------------
__global__ __launch_bounds__(256) void k1_bucket_hist(const int* __restrict__ dst,
                                                      int* __restrict__ H,
                                                      int E, int chunk, int nbuck) {
    __shared__ int cnt[1024];
    for (int i = threadIdx.x; i < nbuck; i += 256) cnt[i] = 0;
    __syncthreads();
    const int g = blockIdx.x;
    const int e0 = g * chunk;
    const int e1 = min(E, e0 + chunk);
    for (int e = e0 + threadIdx.x; e < e1; e += 256)
        atomicAdd(&cnt[dst[e] >> BSHIFT], 1);
    __syncthreads();
    for (int i = threadIdx.x; i < nbuck; i += 256) H[i * NWG + g] = cnt[i];
}

// ---------------- 2-level exclusive scan over PADDED counts ----------------
// Each (wg,bucket) segment is rounded up to 16 ints (one 64B line) so no line
// of packed[] is ever shared by two writers -> no HBM read-modify-write.
__global__ __launch_bounds__(1024) void scan_a(const int* __restrict__ in,
                                               int* __restrict__ out,
                                               int* __restrict__ bsums, int n) {
    __shared__ int sm[1024];
    int i = blockIdx.x * 1024 + threadIdx.x;
    int raw = (i < n) ? in[i] : 0;
    int v = (raw + 15) & ~15;          // pad to 16-int multiple
    sm[threadIdx.x] = v;
    __syncthreads();
    for (int off = 1; off < 1024; off <<= 1) {
        int t = (threadIdx.x >= off) ? sm[threadIdx.x - off] : 0;
        __syncthreads();
        sm[threadIdx.x] += t;
        __syncthreads();
    }
    if (i < n) out[i] = sm[threadIdx.x] - v;  // exclusive (pre block offset)
    if (threadIdx.x == 1023) bsums[blockIdx.x] = sm[1023];
}

__global__ __launch_bounds__(1024) void scan_b(const int* __restrict__ bsums,
                                               int* __restrict__ boffs,
                                               int* __restrict__ ptot, int NB) {
    __shared__ int sm[1024];
    int v = (threadIdx.x < NB) ? bsums[threadIdx.x] : 0;
    sm[threadIdx.x] = v;
    __syncthreads();
    for (int off = 1; off < 1024; off <<= 1) {
        int t = (threadIdx.x >= off) ? sm[threadIdx.x - off] : 0;
        __syncthreads();
        sm[threadIdx.x] += t;
        __syncthreads();
    }
    if (threadIdx.x < NB) boffs[threadIdx.x] = sm[threadIdx.x] - v;
    if (threadIdx.x == NB - 1) ptot[0] = sm[threadIdx.x];  // padded grand total
}

// ---------------- K3: binned append of packed (dstlow7<<17 | src17) --------
// Appends into 64B-aligned private segments; fills segment tails with SENT so
// every line is fully written by exactly one workgroup.
__global__ __launch_bounds__(256) void k3_bin(const int* __restrict__ src,
                                              const int* __restrict__ dst,
                                              const int* __restrict__ O,
                                              const int* __restrict__ boffs,
                                              int* __restrict__ packed,
                                              int E, int chunk, int nbuck) {
    __shared__ int cur[1024];
    const int g = blockIdx.x;
    for (int i = threadIdx.x; i < nbuck; i += 256) {
        const int fi = i * NWG + g;
        cur[i] = O[fi] + boffs[fi >> 10];
    }
    __syncthreads();
    const int e0 = g * chunk;
    const int e1 = min(E, e0 + chunk);
    for (int e = e0 + threadIdx.x; e < e1; e += 256) {
        const int d = dst[e];
        const int b = d >> BSHIFT;
        const int pos = atomicAdd(&cur[b], 1);
        packed[pos] = ((d & (NPB - 1)) << 17) | src[e];
    }
    __syncthreads();
    // pad each of this WG's segments to the 16-int boundary with sentinels
    // (segment starts are 16-aligned by construction, so this completes lines)
    for (int i = threadIdx.x; i < nbuck; i += 256) {
        const int c = cur[i];
        const int end = (c + 15) & ~15;
        for (int j = c; j < end; ++j) packed[j] = SENT;
    }
}

// ---------------- K4: within-bucket sort (LDS-staged, in-place) ------------
// Stages the bucket's padded segment into LDS (48KB), counts/scans there,
// then scatters compact column indices back into packed[] in place.
__global__ __launch_bounds__(256) void k4_local_sort(const int* __restrict__ O,
                                                     const int* __restrict__ boffs,
                                                     const int* __restrict__ ptot,
                                                     int* __restrict__ packed,
                                                     int* __restrict__ rowbeg,
                                                     int* __restrict__ rowend,
                                                     float* __restrict__ dinv,
                                                     int N, int nbuck) {
    __shared__ int sseg[SEGCAP];
    __shared__ int lcnt[NPB];
    __shared__ int s[NPB];
    __shared__ int lpos[NPB];
    const int b = blockIdx.x;
    const int ib = b * NWG;
    const int segbeg = O[ib] + boffs[ib >> 10];
    int segend;
    if (b + 1 < nbuck) {
        const int ie = (b + 1) * NWG;
        segend = O[ie] + boffs[ie >> 10];
    } else {
        segend = ptot[0];
    }
    int seglen = segend - segbeg;
    if (seglen > SEGCAP) seglen = SEGCAP;  // safety clamp; never triggers here
    const int n0 = b << BSHIFT;
    const int ncnt = min(N - n0, NPB);
    const int t = threadIdx.x;

    if (t < NPB) lcnt[t] = 0;
    // coalesced load of the whole segment (incl. sentinels) into LDS
    for (int i = t; i < seglen; i += 256) sseg[i] = packed[segbeg + i];
    __syncthreads();
    for (int i = t; i < seglen; i += 256) {
        const int p = sseg[i];
        if (p >= 0) atomicAdd(&lcnt[(p >> 17) & (NPB - 1)], 1);
    }
    __syncthreads();
    // inclusive scan of lcnt into s (first NPB threads; barriers wave-uniform)
    if (t < NPB) s[t] = lcnt[t];
    __syncthreads();
    for (int off = 1; off < NPB; off <<= 1) {
        int v = 0;
        if (t < NPB && t >= off) v = s[t - off];
        __syncthreads();
        if (t < NPB) s[t] += v;
        __syncthreads();
    }
    if (t < NPB) {
        const int excl = s[t] - lcnt[t];
        lpos[t] = excl;
        if (t < ncnt) {
            rowbeg[n0 + t] = segbeg + excl;
            rowend[n0 + t] = segbeg + s[t];
            dinv[n0 + t] = rsqrtf((float)(lcnt[t] + 1));  // +1 self-loop
        }
    }
    __syncthreads();
    // scatter compact col values back into packed[] (reads all from LDS)
    for (int i = t; i < seglen; i += 256) {
        const int p = sseg[i];
        if (p >= 0) {
            const int dl = (p >> 17) & (NPB - 1);
            const int pos = segbeg + atomicAdd(&lpos[dl], 1);
            packed[pos] = p & 0x1FFFF;
        }
    }
}

// ---------------- h2 = bf16((x @ W) * dinv[row])  via bf16x3 MFMA ----------------
// 512 threads = 8 waves; each wave computes 32 rows (two 16-row tiles) x 64 cols.
__global__ __launch_bounds__(512) void gemm_mfma_kernel(const float* __restrict__ x,
                                                        const float* __restrict__ W,
                                                        const float* __restrict__ dinv,
                                                        unsigned short* __restrict__ h2,
                                                        int N) {
    __shared__ unsigned short Whi[COUT * WPAD];
    __shared__ unsigned short Wlo[COUT * WPAD];
    for (int i = threadIdx.x; i < CIN * COUT; i += 512) {
        int k = i >> 6, c = i & 63;
        float w = W[i];
        unsigned u = fbits(w);
        unsigned short h = (unsigned short)(u >> 16);  // trunc split
        float r = w - bbits(u & 0xFFFF0000u);
        Whi[c * WPAD + k] = h;
        Wlo[c * WPAD + k] = (unsigned short)(fbits(r) >> 16);
    }
    __syncthreads();

    const int lane = threadIdx.x & 63;
    const int wave = threadIdx.x >> 6;
    const int m = lane & 15;
    const int q = lane >> 4;
    const int row0 = blockIdx.x * 256 + wave * 32;

    int ar0 = row0 + m;
    int ar1 = row0 + 16 + m;
    if (ar0 >= N) ar0 = N - 1;  // clamp; stores are guarded
    if (ar1 >= N) ar1 = N - 1;
    const float* __restrict__ xr0 = x + (size_t)ar0 * CIN + q * 8;
    const float* __restrict__ xr1 = x + (size_t)ar1 * CIN + q * 8;

    floatx4 acc0[4] = {floatx4{0,0,0,0}, floatx4{0,0,0,0}, floatx4{0,0,0,0}, floatx4{0,0,0,0}};
    floatx4 acc1[4] = {floatx4{0,0,0,0}, floatx4{0,0,0,0}, floatx4{0,0,0,0}, floatx4{0,0,0,0}};

#pragma unroll
    for (int kc = 0; kc < 8; ++kc) {
        floatx4 a00 = *(const floatx4*)(xr0 + kc * 32);
        floatx4 a01 = *(const floatx4*)(xr0 + kc * 32 + 4);
        floatx4 a10 = *(const floatx4*)(xr1 + kc * 32);
        floatx4 a11 = *(const floatx4*)(xr1 + kc * 32 + 4);
        short8 ahi0, alo0, ahi1, alo1;
        split8(a00, a01, ahi0, alo0);
        split8(a10, a11, ahi1, alo1);
        const int kb = kc * 32 + q * 8;
#pragma unroll
        for (int ct = 0; ct < 4; ++ct) {
            const int c = ct * 16 + m;
            short8 bhi = *(const short8*)&Whi[c * WPAD + kb];
            short8 blo = *(const short8*)&Wlo[c * WPAD + kb];
            acc0[ct] = __builtin_amdgcn_mfma_f32_16x16x32_bf16(ahi0, bhi, acc0[ct], 0, 0, 0);
            acc0[ct] = __builtin_amdgcn_mfma_f32_16x16x32_bf16(ahi0, blo, acc0[ct], 0, 0, 0);
            acc0[ct] = __builtin_amdgcn_mfma_f32_16x16x32_bf16(alo0, bhi, acc0[ct], 0, 0, 0);
            acc1[ct] = __builtin_amdgcn_mfma_f32_16x16x32_bf16(ahi1, bhi, acc1[ct], 0, 0, 0);
            acc1[ct] = __builtin_amdgcn_mfma_f32_16x16x32_bf16(ahi1, blo, acc1[ct], 0, 0, 0);
            acc1[ct] = __builtin_amdgcn_mfma_f32_16x16x32_bf16(alo1, bhi, acc1[ct], 0, 0, 0);
        }
    }

    // C/D layout: col = lane&15 (= m), row = q*4 + reg
#pragma unroll
    for (int t = 0; t < 2; ++t) {
#pragma unroll
        for (int r = 0; r < 4; ++r) {
            const int row = row0 + t * 16 + q * 4 + r;
            if (row < N) {
                const float dv = dinv[row];
                unsigned short* __restrict__ op = h2 + (size_t)row * COUT;
#pragma unroll
                for (int ct = 0; ct < 4; ++ct) {
                    float v = (t == 0) ? acc0[ct][r] : acc1[ct][r];
                    op[ct * 16 + m] = f2bf(v * dv);
                }
            }
        }
    }
}

// ---------------- pull-gather: one wave per node, lane = channel PAIR ----------------
// half h = lane>>5 handles edges of parity h; c = lane&31 is the dword (2-channel) idx.
// Main loop: 16 edges/iter (8 h2 rows in flight per wave) with next-group col
// prefetch, so the steady-state chain is one h2 latency, not col+h2.
__global__ __launch_bounds__(256) void gather_kernel(const unsigned short* __restrict__ h2,
                                                     const int* __restrict__ rowbeg,
                                                     const int* __restrict__ rowend,
                                                     const int* __restrict__ col,
                                                     const float* __restrict__ dinv,
                                                     const float* __restrict__ b,
                                                     float* __restrict__ out, int N) {
    const int lane = threadIdx.x & 63;
    const int h = lane >> 5;
    const int c = lane & 31;
    const int node = blockIdx.x * 4 + (threadIdx.x >> 6);
    if (node >= N) return;
    const unsigned* __restrict__ h2u = (const unsigned*)h2;
    const int p0 = rowbeg[node];
    const int p1 = rowend[node];
    float a0 = 0.f, a1 = 0.f;
    int p = p0;

    const int nmain = (p1 - p0) >> 4;   // 16-edge iterations
    if (nmain > 0) {
        // preload col group 0 (8 edges per half)
        int e0 = col[p + h],      e1 = col[p + 2 + h];
        int e2 = col[p + 4 + h],  e3 = col[p + 6 + h];
        int e4 = col[p + 8 + h],  e5 = col[p + 10 + h];
        int e6 = col[p + 12 + h], e7 = col[p + 14 + h];
        for (int it = 0; it < nmain; ++it) {
            const unsigned u0 = h2u[(size_t)e0 * 32 + c];
            const unsigned u1 = h2u[(size_t)e1 * 32 + c];
            const unsigned u2 = h2u[(size_t)e2 * 32 + c];
            const unsigned u3 = h2u[(size_t)e3 * 32 + c];
            const unsigned u4 = h2u[(size_t)e4 * 32 + c];
            const unsigned u5 = h2u[(size_t)e5 * 32 + c];
            const unsigned u6 = h2u[(size_t)e6 * 32 + c];
            const unsigned u7 = h2u[(size_t)e7 * 32 + c];
            const int pn = p + 16;
            if (it + 1 < nmain) {  // prefetch next col group while h2 loads fly
                e0 = col[pn + h];      e1 = col[pn + 2 + h];
                e2 = col[pn + 4 + h];  e3 = col[pn + 6 + h];
                e4 = col[pn + 8 + h];  e5 = col[pn + 10 + h];
                e6 = col[pn + 12 + h]; e7 = col[pn + 14 + h];
            }
            a0 += ((bbits(u0 << 16) + bbits(u1 << 16)) + (bbits(u2 << 16) + bbits(u3 << 16))) +
                  ((bbits(u4 << 16) + bbits(u5 << 16)) + (bbits(u6 << 16) + bbits(u7 << 16)));
            a1 += ((bbits(u0 & 0xFFFF0000u) + bbits(u1 & 0xFFFF0000u)) +
                   (bbits(u2 & 0xFFFF0000u) + bbits(u3 & 0xFFFF0000u))) +
                  ((bbits(u4 & 0xFFFF0000u) + bbits(u5 & 0xFFFF0000u)) +
                   (bbits(u6 & 0xFFFF0000u) + bbits(u7 & 0xFFFF0000u)));
            p = pn;
        }
    }
    // 8-edge leftover (runs at most once)
    for (; p + 7 < p1; p += 8) {
        const int e0 = col[p + h],     e1 = col[p + 2 + h];
        const int e2 = col[p + 4 + h], e3 = col[p + 6 + h];
        const unsigned u0 = h2u[(size_t)e0 * 32 + c];
        const unsigned u1 = h2u[(size_t)e1 * 32 + c];
        const unsigned u2 = h2u[(size_t)e2 * 32 + c];
        const unsigned u3 = h2u[(size_t)e3 * 32 + c];
        a0 += (bbits(u0 << 16) + bbits(u1 << 16)) + (bbits(u2 << 16) + bbits(u3 << 16));
        a1 += (bbits(u0 & 0xFFFF0000u) + bbits(u1 & 0xFFFF0000u)) +
              (bbits(u2 & 0xFFFF0000u) + bbits(u3 & 0xFFFF0000u));
    }
    for (; p + 1 < p1; p += 2) {
        const int e = col[p + h];
        const unsigned u = h2u[(size_t)e * 32 + c];
        a0 += bbits(u << 16);
        a1 += bbits(u & 0xFFFF0000u);
    }
    if (p < p1 && h == 0) {  // odd leftover edge: half 0 only
        const unsigned u = h2u[(size_t)col[p] * 32 + c];
        a0 += bbits(u << 16);
        a1 += bbits(u & 0xFFFF0000u);
    }
    // combine edge-parity halves
    a0 += __shfl_xor(a0, 32, 64);
    a1 += __shfl_xor(a1, 32, 64);
    if (h == 0) {
        const unsigned su = h2u[(size_t)node * 32 + c];  // self-loop term
        const float dv = dinv[node];
        const float2 bb = ((const float2*)b)[c];
        float2 o;
        o.x = (a0 + bbits(su << 16)) * dv + bb.x;
        o.y = (a1 + bbits(su & 0xFFFF0000u)) * dv + bb.y;
        ((float2*)out)[(size_t)node * 32 + c] = o;
    }
}

// ---------------- launch ----------------
extern "C" void kernel_launch(void* const* d_in, const int* in_sizes, int n_in,
                              void* d_out, int out_size, void* d_ws, size_t ws_size,
                              hipStream_t stream) {
    const float* x = (const float*)d_in[0];
    const int* ei = (const int*)d_in[1];
    const float* W = (const float*)d_in[2];
    const float* b = (const float*)d_in[3];
    float* out = (float*)d_out;

    const int N = in_sizes[0] / CIN;
    const int E = in_sizes[1] / 2;
    const int* src = ei;
    const int* dst = ei + E;

    const int nbuck = (N + NPB - 1) >> BSHIFT;        // 782
    const int nH = nbuck * NWG;                        // 200192
    const int chunk = (E + NWG - 1) / NWG;             // 12500
    const int NBs = (nH + 1023) / 1024;                // 196 (must be <= 1024)
    const int padcap = E + 16 * nH;                    // worst-case padded extent

    // workspace layout (256 B aligned chunks); total ~41.3 MB
    auto align_up = [](size_t v) { return (v + 255) & ~(size_t)255; };
    char* ws = (char*)d_ws;
    size_t off = 0;
    int* H = (int*)(ws + off);        off = align_up(off + (size_t)nH * 4);
    int* O = (int*)(ws + off);        off = align_up(off + (size_t)nH * 4);
    int* bsums = (int*)(ws + off);    off = align_up(off + (size_t)NBs * 4);
    int* boffs = (int*)(ws + off);    off = align_up(off + (size_t)NBs * 4);
    int* ptot = (int*)(ws + off);     off = align_up(off + 4);
    int* rowbeg = (int*)(ws + off);   off = align_up(off + (size_t)N * 4);
    int* rowend = (int*)(ws + off);   off = align_up(off + (size_t)N * 4);
    float* dinv = (float*)(ws + off); off = align_up(off + (size_t)N * 4);
    int* packed = (int*)(ws + off);   off = align_up(off + (size_t)padcap * 4);
    unsigned short* h2 = (unsigned short*)(ws + off);
    off = align_up(off + (size_t)N * COUT * 2);
    (void)ws_size;

    // 1. per-workgroup bucket histogram
    k1_bucket_hist<<<NWG, 256, 0, stream>>>(dst, H, E, chunk, nbuck);
    // 2-3. exclusive scan of line-padded H -> 64B-aligned private ranges O
    scan_a<<<NBs, 1024, 0, stream>>>(H, O, bsums, nH);
    scan_b<<<1, 1024, 0, stream>>>(bsums, boffs, ptot, NBs);
    // 4. binned append into exclusive 64B lines + sentinel pad
    k3_bin<<<NWG, 256, 0, stream>>>(src, dst, O, boffs, packed, E, chunk, nbuck);
    // 5. within-bucket counting sort, LDS-staged, in-place -> rowbeg/rowend, dinv
    k4_local_sort<<<nbuck, 256, 0, stream>>>(O, boffs, ptot, packed, rowbeg, rowend, dinv, N, nbuck);
    // 6. projection h2 = bf16((x@W)*dinv) via bf16x3 MFMA, 32 rows/wave
    gemm_mfma_kernel<<<(N + 255) / 256, 512, 0, stream>>>(x, W, dinv, h2, N);
    // 7. pull-gather + bias (16-edge pipelined main loop, col prefetch; col==packed)
    gather_kernel<<<(N + 3) / 4, 256, 0, stream>>>(h2, rowbeg, rowend, packed, dinv, b, out, N);
}

// Round 7
// 333.950 us; speedup vs baseline: 1.1602x; 1.1602x over previous
//
#include <hip/hip_runtime.h>
#include <hip/hip_bf16.h>

#define CIN 256
#define COUT 64
#define WPAD 264       // padded K stride for transposed W in LDS
#define BSHIFT 8       // nodes per bucket = 256
#define NPB 256        // nodes per bucket
#define NWG 512        // workgroups for binning passes (2 blocks/CU)
#define SENT ((int)0x80000000u)  // sentinel pad word in packed[]
#define SEGCAP 13312   // k4 LDS staging capacity for one bucket segment (ints)
#define SCAP 12160     // k3 LDS stage capacity (>= chunk 6250 + 15*nbuck 391)

typedef __attribute__((ext_vector_type(8))) short short8;
typedef __attribute__((ext_vector_type(4))) float floatx4;

static __device__ __forceinline__ unsigned int fbits(float f) {
    return __builtin_bit_cast(unsigned int, f);
}
static __device__ __forceinline__ float bbits(unsigned int u) {
    return __builtin_bit_cast(float, u);
}
// RTN fp32->bf16 (gemm epilogue only)
static __device__ __forceinline__ unsigned short f2bf(float f) {
    unsigned u = fbits(f);
    return (unsigned short)((u + 0x7FFFu + ((u >> 16) & 1u)) >> 16);
}

// truncation-split of 8 fp32 into bf16 hi/lo short8 fragments (v_perm packing).
union U8 { short8 s; unsigned int u[4]; };
static __device__ __forceinline__ void split8(floatx4 a0, floatx4 a1,
                                              short8& hi, short8& lo) {
    float f[8] = {a0[0], a0[1], a0[2], a0[3], a1[0], a1[1], a1[2], a1[3]};
    U8 H, L;
#pragma unroll
    for (int j = 0; j < 4; ++j) {
        unsigned u0 = fbits(f[2 * j]);
        unsigned u1 = fbits(f[2 * j + 1]);
        H.u[j] = __builtin_amdgcn_perm(u1, u0, 0x07060302u);
        float r0 = f[2 * j] - bbits(u0 & 0xFFFF0000u);
        float r1 = f[2 * j + 1] - bbits(u1 & 0xFFFF0000u);
        L.u[j] = __builtin_amdgcn_perm(fbits(r1), fbits(r0), 0x07060302u);
    }
    hi = H.s;
    lo = L.s;
}

// ---------------- K1: per-workgroup bucket histogram ----------------
__global__ __launch_bounds__(256) void k1_bucket_hist(const int* __restrict__ dst,
                                                      int* __restrict__ H,
                                                      int E, int chunk, int nbuck) {
    __shared__ int cnt[512];
    for (int i = threadIdx.x; i < 512; i += 256) cnt[i] = 0;
    __syncthreads();
    const int g = blockIdx.x;
    const int e0 = g * chunk;
    const int e1 = min(E, e0 + chunk);
    for (int e = e0 + threadIdx.x; e < e1; e += 256)
        atomicAdd(&cnt[dst[e] >> BSHIFT], 1);
    __syncthreads();
    for (int i = threadIdx.x; i < nbuck; i += 256) H[i * NWG + g] = cnt[i];
}

// ---------------- 2-level exclusive scan over PADDED counts ----------------
// Each (wg,bucket) segment is rounded up to 16 ints (one 64B line) so every
// line of packed[] has exactly one writer.
__global__ __launch_bounds__(1024) void scan_a(const int* __restrict__ in,
                                               int* __restrict__ out,
                                               int* __restrict__ bsums, int n) {
    __shared__ int sm[1024];
    int i = blockIdx.x * 1024 + threadIdx.x;
    int raw = (i < n) ? in[i] : 0;
    int v = (raw + 15) & ~15;          // pad to 16-int multiple
    sm[threadIdx.x] = v;
    __syncthreads();
    for (int off = 1; off < 1024; off <<= 1) {
        int t = (threadIdx.x >= off) ? sm[threadIdx.x - off] : 0;
        __syncthreads();
        sm[threadIdx.x] += t;
        __syncthreads();
    }
    if (i < n) out[i] = sm[threadIdx.x] - v;  // exclusive (pre block offset)
    if (threadIdx.x == 1023) bsums[blockIdx.x] = sm[1023];
}

__global__ __launch_bounds__(1024) void scan_b(const int* __restrict__ bsums,
                                               int* __restrict__ boffs,
                                               int* __restrict__ ptot, int NB) {
    __shared__ int sm[1024];
    int v = (threadIdx.x < NB) ? bsums[threadIdx.x] : 0;
    sm[threadIdx.x] = v;
    __syncthreads();
    for (int off = 1; off < 1024; off <<= 1) {
        int t = (threadIdx.x >= off) ? sm[threadIdx.x - off] : 0;
        __syncthreads();
        sm[threadIdx.x] += t;
        __syncthreads();
    }
    if (threadIdx.x < NB) boffs[threadIdx.x] = sm[threadIdx.x] - v;
    if (threadIdx.x == NB - 1) ptot[0] = sm[threadIdx.x];  // padded grand total
}

// ---------------- K3: LDS-staged binned append (full-line flush) -----------
// Phase 1: scatter this WG's chunk into a compact LDS image laid out as the
// concatenation of its pad16 bucket segments (pre-filled with SENT).
// Phase 2: wave-per-bucket copy LDS segment -> global segment as aligned
// dwordx4 stores: every 64B HBM line is written fully, once, by one WG.
__global__ __launch_bounds__(256) void k3_bin(const int* __restrict__ src,
                                              const int* __restrict__ dst,
                                              const int* __restrict__ H,
                                              const int* __restrict__ O,
                                              const int* __restrict__ boffs,
                                              int* __restrict__ packed,
                                              int E, int chunk, int nbuck) {
    __shared__ int stage[SCAP];
    __shared__ int lcur[512];   // scan workspace -> exclusive local offsets
    __shared__ int lfill[512];  // atomic fill cursors (local)
    __shared__ int gbase[512];  // global segment bases
    const int g = blockIdx.x;
    const int t = threadIdx.x;

    for (int i = t; i < SCAP; i += 256) stage[i] = SENT;
    for (int i = t; i < 512; i += 256) {
        int c = (i < nbuck) ? H[i * NWG + g] : 0;
        gbase[i] = c;                      // stash raw count temporarily
        lcur[i] = (c + 15) & ~15;          // padded count for local scan
    }
    __syncthreads();
    // Hillis-Steele inclusive scan over 512 entries, 2 per thread
    for (int off = 1; off < 512; off <<= 1) {
        const int i0 = t, i1 = t + 256;
        const int v0 = (i0 >= off) ? lcur[i0 - off] : 0;
        const int v1 = (i1 >= off) ? lcur[i1 - off] : 0;
        __syncthreads();
        lcur[i0] += v0;
        lcur[i1] += v1;
        __syncthreads();
    }
    for (int i = t; i < nbuck; i += 256) {
        const int pad = (gbase[i] + 15) & ~15;
        const int excl = lcur[i] - pad;    // exclusive padded prefix
        lcur[i] = excl;
        lfill[i] = excl;
        const int fi = i * NWG + g;
        gbase[i] = O[fi] + boffs[fi >> 10];
    }
    __syncthreads();

    // phase 1: scatter into LDS stage
    const int e0 = g * chunk;
    const int e1 = min(E, e0 + chunk);
    for (int e = e0 + t; e < e1; e += 256) {
        const int d = dst[e];
        const int b = d >> BSHIFT;
        const int pos = atomicAdd(&lfill[b], 1);
        stage[pos] = ((d & (NPB - 1)) << 17) | src[e];
    }
    __syncthreads();

    // phase 2: full-line flush, one bucket per wave round-robin
    const int wave = t >> 6;
    const int lane = t & 63;
    for (int b = wave; b < nbuck; b += 4) {
        const int lo = lcur[b];
        const int n16 = (lfill[b] - lo + 15) & ~15;   // padded segment length
        const int n4 = n16 >> 2;
        int* __restrict__ gp = packed + gbase[b];
        for (int k = lane; k < n4; k += 64) {
            const int4 v = *(const int4*)&stage[lo + 4 * k];
            *(int4*)&gp[4 * k] = v;
        }
    }
}

// ---------------- K4: within-bucket sort (LDS-staged, in-place) ------------
// Stages the bucket's padded segment into LDS, counts/scans there, then
// scatters compact column indices back into packed[] in place.
__global__ __launch_bounds__(256) void k4_local_sort(const int* __restrict__ O,
                                                     const int* __restrict__ boffs,
                                                     const int* __restrict__ ptot,
                                                     int* __restrict__ packed,
                                                     int* __restrict__ rowbeg,
                                                     int* __restrict__ rowend,
                                                     float* __restrict__ dinv,
                                                     int N, int nbuck) {
    __shared__ int sseg[SEGCAP];
    __shared__ int lcnt[NPB];
    __shared__ int s[NPB];
    __shared__ int lpos[NPB];
    const int b = blockIdx.x;
    const int ib = b * NWG;
    const int segbeg = O[ib] + boffs[ib >> 10];
    int segend;
    if (b + 1 < nbuck) {
        const int ie = (b + 1) * NWG;
        segend = O[ie] + boffs[ie >> 10];
    } else {
        segend = ptot[0];
    }
    int seglen = segend - segbeg;
    if (seglen > SEGCAP) seglen = SEGCAP;  // safety clamp; never triggers here
    const int n0 = b << BSHIFT;
    const int ncnt = min(N - n0, NPB);
    const int t = threadIdx.x;

    lcnt[t] = 0;
    // coalesced load of the whole segment (incl. sentinels) into LDS
    for (int i = t; i < seglen; i += 256) sseg[i] = packed[segbeg + i];
    __syncthreads();
    for (int i = t; i < seglen; i += 256) {
        const int p = sseg[i];
        if (p >= 0) atomicAdd(&lcnt[(p >> 17) & (NPB - 1)], 1);
    }
    __syncthreads();
    // inclusive scan of lcnt into s (NPB == blockDim, unguarded)
    s[t] = lcnt[t];
    __syncthreads();
    for (int off = 1; off < NPB; off <<= 1) {
        int v = (t >= off) ? s[t - off] : 0;
        __syncthreads();
        s[t] += v;
        __syncthreads();
    }
    const int excl = s[t] - lcnt[t];
    lpos[t] = excl;
    if (t < ncnt) {
        rowbeg[n0 + t] = segbeg + excl;
        rowend[n0 + t] = segbeg + s[t];
        dinv[n0 + t] = rsqrtf((float)(lcnt[t] + 1));  // +1 self-loop
    }
    __syncthreads();
    // scatter compact col values back into packed[] (reads all from LDS)
    for (int i = t; i < seglen; i += 256) {
        const int p = sseg[i];
        if (p >= 0) {
            const int dl = (p >> 17) & (NPB - 1);
            const int pos = segbeg + atomicAdd(&lpos[dl], 1);
            packed[pos] = p & 0x1FFFF;
        }
    }
}

// ---------------- h2 = bf16((x @ W) * dinv[row])  via bf16x3 MFMA ----------------
// 512 threads = 8 waves; each wave computes 32 rows (two 16-row tiles) x 64 cols.
__global__ __launch_bounds__(512) void gemm_mfma_kernel(const float* __restrict__ x,
                                                        const float* __restrict__ W,
                                                        const float* __restrict__ dinv,
                                                        unsigned short* __restrict__ h2,
                                                        int N) {
    __shared__ unsigned short Whi[COUT * WPAD];
    __shared__ unsigned short Wlo[COUT * WPAD];
    for (int i = threadIdx.x; i < CIN * COUT; i += 512) {
        int k = i >> 6, c = i & 63;
        float w = W[i];
        unsigned u = fbits(w);
        unsigned short h = (unsigned short)(u >> 16);  // trunc split
        float r = w - bbits(u & 0xFFFF0000u);
        Whi[c * WPAD + k] = h;
        Wlo[c * WPAD + k] = (unsigned short)(fbits(r) >> 16);
    }
    __syncthreads();

    const int lane = threadIdx.x & 63;
    const int wave = threadIdx.x >> 6;
    const int m = lane & 15;
    const int q = lane >> 4;
    const int row0 = blockIdx.x * 256 + wave * 32;

    int ar0 = row0 + m;
    int ar1 = row0 + 16 + m;
    if (ar0 >= N) ar0 = N - 1;  // clamp; stores are guarded
    if (ar1 >= N) ar1 = N - 1;
    const float* __restrict__ xr0 = x + (size_t)ar0 * CIN + q * 8;
    const float* __restrict__ xr1 = x + (size_t)ar1 * CIN + q * 8;

    floatx4 acc0[4] = {floatx4{0,0,0,0}, floatx4{0,0,0,0}, floatx4{0,0,0,0}, floatx4{0,0,0,0}};
    floatx4 acc1[4] = {floatx4{0,0,0,0}, floatx4{0,0,0,0}, floatx4{0,0,0,0}, floatx4{0,0,0,0}};

#pragma unroll
    for (int kc = 0; kc < 8; ++kc) {
        floatx4 a00 = *(const floatx4*)(xr0 + kc * 32);
        floatx4 a01 = *(const floatx4*)(xr0 + kc * 32 + 4);
        floatx4 a10 = *(const floatx4*)(xr1 + kc * 32);
        floatx4 a11 = *(const floatx4*)(xr1 + kc * 32 + 4);
        short8 ahi0, alo0, ahi1, alo1;
        split8(a00, a01, ahi0, alo0);
        split8(a10, a11, ahi1, alo1);
        const int kb = kc * 32 + q * 8;
#pragma unroll
        for (int ct = 0; ct < 4; ++ct) {
            const int c = ct * 16 + m;
            short8 bhi = *(const short8*)&Whi[c * WPAD + kb];
            short8 blo = *(const short8*)&Wlo[c * WPAD + kb];
            acc0[ct] = __builtin_amdgcn_mfma_f32_16x16x32_bf16(ahi0, bhi, acc0[ct], 0, 0, 0);
            acc0[ct] = __builtin_amdgcn_mfma_f32_16x16x32_bf16(ahi0, blo, acc0[ct], 0, 0, 0);
            acc0[ct] = __builtin_amdgcn_mfma_f32_16x16x32_bf16(alo0, bhi, acc0[ct], 0, 0, 0);
            acc1[ct] = __builtin_amdgcn_mfma_f32_16x16x32_bf16(ahi1, bhi, acc1[ct], 0, 0, 0);
            acc1[ct] = __builtin_amdgcn_mfma_f32_16x16x32_bf16(ahi1, blo, acc1[ct], 0, 0, 0);
            acc1[ct] = __builtin_amdgcn_mfma_f32_16x16x32_bf16(alo1, bhi, acc1[ct], 0, 0, 0);
        }
    }

    // C/D layout: col = lane&15 (= m), row = q*4 + reg
#pragma unroll
    for (int t = 0; t < 2; ++t) {
#pragma unroll
        for (int r = 0; r < 4; ++r) {
            const int row = row0 + t * 16 + q * 4 + r;
            if (row < N) {
                const float dv = dinv[row];
                unsigned short* __restrict__ op = h2 + (size_t)row * COUT;
#pragma unroll
                for (int ct = 0; ct < 4; ++ct) {
                    float v = (t == 0) ? acc0[ct][r] : acc1[ct][r];
                    op[ct * 16 + m] = f2bf(v * dv);
                }
            }
        }
    }
}

// ---------------- pull-gather: one wave per node, lane = channel PAIR ----------------
// half h = lane>>5 handles edges of parity h; c = lane&31 is the dword (2-channel) idx.
// Main loop: 16 edges/iter (8 h2 rows in flight per wave) with next-group col
// prefetch, so the steady-state chain is one h2 latency, not col+h2.
__global__ __launch_bounds__(256) void gather_kernel(const unsigned short* __restrict__ h2,
                                                     const int* __restrict__ rowbeg,
                                                     const int* __restrict__ rowend,
                                                     const int* __restrict__ col,
                                                     const float* __restrict__ dinv,
                                                     const float* __restrict__ b,
                                                     float* __restrict__ out, int N) {
    const int lane = threadIdx.x & 63;
    const int h = lane >> 5;
    const int c = lane & 31;
    const int node = blockIdx.x * 4 + (threadIdx.x >> 6);
    if (node >= N) return;
    const unsigned* __restrict__ h2u = (const unsigned*)h2;
    const int p0 = rowbeg[node];
    const int p1 = rowend[node];
    float a0 = 0.f, a1 = 0.f;
    int p = p0;

    const int nmain = (p1 - p0) >> 4;   // 16-edge iterations
    if (nmain > 0) {
        // preload col group 0 (8 edges per half)
        int e0 = col[p + h],      e1 = col[p + 2 + h];
        int e2 = col[p + 4 + h],  e3 = col[p + 6 + h];
        int e4 = col[p + 8 + h],  e5 = col[p + 10 + h];
        int e6 = col[p + 12 + h], e7 = col[p + 14 + h];
        for (int it = 0; it < nmain; ++it) {
            const unsigned u0 = h2u[(size_t)e0 * 32 + c];
            const unsigned u1 = h2u[(size_t)e1 * 32 + c];
            const unsigned u2 = h2u[(size_t)e2 * 32 + c];
            const unsigned u3 = h2u[(size_t)e3 * 32 + c];
            const unsigned u4 = h2u[(size_t)e4 * 32 + c];
            const unsigned u5 = h2u[(size_t)e5 * 32 + c];
            const unsigned u6 = h2u[(size_t)e6 * 32 + c];
            const unsigned u7 = h2u[(size_t)e7 * 32 + c];
            const int pn = p + 16;
            if (it + 1 < nmain) {  // prefetch next col group while h2 loads fly
                e0 = col[pn + h];      e1 = col[pn + 2 + h];
                e2 = col[pn + 4 + h];  e3 = col[pn + 6 + h];
                e4 = col[pn + 8 + h];  e5 = col[pn + 10 + h];
                e6 = col[pn + 12 + h]; e7 = col[pn + 14 + h];
            }
            a0 += ((bbits(u0 << 16) + bbits(u1 << 16)) + (bbits(u2 << 16) + bbits(u3 << 16))) +
                  ((bbits(u4 << 16) + bbits(u5 << 16)) + (bbits(u6 << 16) + bbits(u7 << 16)));
            a1 += ((bbits(u0 & 0xFFFF0000u) + bbits(u1 & 0xFFFF0000u)) +
                   (bbits(u2 & 0xFFFF0000u) + bbits(u3 & 0xFFFF0000u))) +
                  ((bbits(u4 & 0xFFFF0000u) + bbits(u5 & 0xFFFF0000u)) +
                   (bbits(u6 & 0xFFFF0000u) + bbits(u7 & 0xFFFF0000u)));
            p = pn;
        }
    }
    // 8-edge leftover (runs at most once)
    for (; p + 7 < p1; p += 8) {
        const int e0 = col[p + h],     e1 = col[p + 2 + h];
        const int e2 = col[p + 4 + h], e3 = col[p + 6 + h];
        const unsigned u0 = h2u[(size_t)e0 * 32 + c];
        const unsigned u1 = h2u[(size_t)e1 * 32 + c];
        const unsigned u2 = h2u[(size_t)e2 * 32 + c];
        const unsigned u3 = h2u[(size_t)e3 * 32 + c];
        a0 += (bbits(u0 << 16) + bbits(u1 << 16)) + (bbits(u2 << 16) + bbits(u3 << 16));
        a1 += (bbits(u0 & 0xFFFF0000u) + bbits(u1 & 0xFFFF0000u)) +
              (bbits(u2 & 0xFFFF0000u) + bbits(u3 & 0xFFFF0000u));
    }
    for (; p + 1 < p1; p += 2) {
        const int e = col[p + h];
        const unsigned u = h2u[(size_t)e * 32 + c];
        a0 += bbits(u << 16);
        a1 += bbits(u & 0xFFFF0000u);
    }
    if (p < p1 && h == 0) {  // odd leftover edge: half 0 only
        const unsigned u = h2u[(size_t)col[p] * 32 + c];
        a0 += bbits(u << 16);
        a1 += bbits(u & 0xFFFF0000u);
    }
    // combine edge-parity halves
    a0 += __shfl_xor(a0, 32, 64);
    a1 += __shfl_xor(a1, 32, 64);
    if (h == 0) {
        const unsigned su = h2u[(size_t)node * 32 + c];  // self-loop term
        const float dv = dinv[node];
        const float2 bb = ((const float2*)b)[c];
        float2 o;
        o.x = (a0 + bbits(su << 16)) * dv + bb.x;
        o.y = (a1 + bbits(su & 0xFFFF0000u)) * dv + bb.y;
        ((float2*)out)[(size_t)node * 32 + c] = o;
    }
}

// ---------------- launch ----------------
extern "C" void kernel_launch(void* const* d_in, const int* in_sizes, int n_in,
                              void* d_out, int out_size, void* d_ws, size_t ws_size,
                              hipStream_t stream) {
    const float* x = (const float*)d_in[0];
    const int* ei = (const int*)d_in[1];
    const float* W = (const float*)d_in[2];
    const float* b = (const float*)d_in[3];
    float* out = (float*)d_out;

    const int N = in_sizes[0] / CIN;
    const int E = in_sizes[1] / 2;
    const int* src = ei;
    const int* dst = ei + E;

    const int nbuck = (N + NPB - 1) >> BSHIFT;        // 391
    const int nH = nbuck * NWG;                        // 200192
    const int chunk = (E + NWG - 1) / NWG;             // 6250
    const int NBs = (nH + 1023) / 1024;                // 196 (must be <= 1024)
    const int padcap = E + 16 * nH;                    // worst-case padded extent

    // workspace layout (256 B aligned chunks); total ~41.5 MB
    auto align_up = [](size_t v) { return (v + 255) & ~(size_t)255; };
    char* ws = (char*)d_ws;
    size_t off = 0;
    int* H = (int*)(ws + off);        off = align_up(off + (size_t)nH * 4);
    int* O = (int*)(ws + off);        off = align_up(off + (size_t)nH * 4);
    int* bsums = (int*)(ws + off);    off = align_up(off + (size_t)NBs * 4);
    int* boffs = (int*)(ws + off);    off = align_up(off + (size_t)NBs * 4);
    int* ptot = (int*)(ws + off);     off = align_up(off + 4);
    int* rowbeg = (int*)(ws + off);   off = align_up(off + (size_t)N * 4);
    int* rowend = (int*)(ws + off);   off = align_up(off + (size_t)N * 4);
    float* dinv = (float*)(ws + off); off = align_up(off + (size_t)N * 4);
    int* packed = (int*)(ws + off);   off = align_up(off + (size_t)padcap * 4);
    unsigned short* h2 = (unsigned short*)(ws + off);
    off = align_up(off + (size_t)N * COUT * 2);
    (void)ws_size;

    // 1. per-workgroup bucket histogram
    k1_bucket_hist<<<NWG, 256, 0, stream>>>(dst, H, E, chunk, nbuck);
    // 2-3. exclusive scan of line-padded H -> 64B-aligned private ranges O
    scan_a<<<NBs, 1024, 0, stream>>>(H, O, bsums, nH);
    scan_b<<<1, 1024, 0, stream>>>(bsums, boffs, ptot, NBs);
    // 4. LDS-staged binned append, full-line flush
    k3_bin<<<NWG, 256, 0, stream>>>(src, dst, H, O, boffs, packed, E, chunk, nbuck);
    // 5. within-bucket counting sort, LDS-staged, in-place -> rowbeg/rowend, dinv
    k4_local_sort<<<nbuck, 256, 0, stream>>>(O, boffs, ptot, packed, rowbeg, rowend, dinv, N, nbuck);
    // 6. projection h2 = bf16((x@W)*dinv) via bf16x3 MFMA, 32 rows/wave
    gemm_mfma_kernel<<<(N + 255) / 256, 512, 0, stream>>>(x, W, dinv, h2, N);
    // 7. pull-gather + bias (16-edge pipelined main loop, col prefetch; col==packed)
    gather_kernel<<<(N + 3) / 4, 256, 0, stream>>>(h2, rowbeg, rowend, packed, dinv, b, out, N);
}

// Round 9
// 328.363 us; speedup vs baseline: 1.1799x; 1.0170x over previous
//
#include <hip/hip_runtime.h>
#include <hip/hip_bf16.h>

#define CIN 256
#define COUT 64
#define WPAD 264       // padded K stride for transposed W in LDS
#define BSHIFT 8       // nodes per bucket = 256
#define NPB 256        // nodes per bucket
#define NWG 512        // workgroups for binning passes (2 blocks/CU)
#define SENT ((int)0x80000000u)  // sentinel pad word in packed[]
#define SEGCAP 13312   // k4 LDS staging capacity for one bucket segment (ints)
#define SCAP 12160     // k3 LDS stage capacity (>= chunk 6250 + 15*nbuck 391)

typedef __attribute__((ext_vector_type(8))) short short8;
typedef __attribute__((ext_vector_type(4))) float floatx4;

static __device__ __forceinline__ unsigned int fbits(float f) {
    return __builtin_bit_cast(unsigned int, f);
}
static __device__ __forceinline__ float bbits(unsigned int u) {
    return __builtin_bit_cast(float, u);
}
// RTN fp32->bf16 (gemm epilogue only)
static __device__ __forceinline__ unsigned short f2bf(float f) {
    unsigned u = fbits(f);
    return (unsigned short)((u + 0x7FFFu + ((u >> 16) & 1u)) >> 16);
}

// truncation-split of 8 fp32 into bf16 hi/lo short8 fragments (v_perm packing).
union U8 { short8 s; unsigned int u[4]; };
static __device__ __forceinline__ void split8(floatx4 a0, floatx4 a1,
                                              short8& hi, short8& lo) {
    float f[8] = {a0[0], a0[1], a0[2], a0[3], a1[0], a1[1], a1[2], a1[3]};
    U8 H, L;
#pragma unroll
    for (int j = 0; j < 4; ++j) {
        unsigned u0 = fbits(f[2 * j]);
        unsigned u1 = fbits(f[2 * j + 1]);
        H.u[j] = __builtin_amdgcn_perm(u1, u0, 0x07060302u);
        float r0 = f[2 * j] - bbits(u0 & 0xFFFF0000u);
        float r1 = f[2 * j + 1] - bbits(u1 & 0xFFFF0000u);
        L.u[j] = __builtin_amdgcn_perm(fbits(r1), fbits(r0), 0x07060302u);
    }
    hi = H.s;
    lo = L.s;
}

// ---------------- K1: per-workgroup bucket histogram ----------------
__global__ __launch_bounds__(256) void k1_bucket_hist(const int* __restrict__ dst,
                                                      int* __restrict__ H,
                                                      int E, int chunk, int nbuck) {
    __shared__ int cnt[512];
    for (int i = threadIdx.x; i < 512; i += 256) cnt[i] = 0;
    __syncthreads();
    const int g = blockIdx.x;
    const int e0 = g * chunk;
    const int e1 = min(E, e0 + chunk);
    for (int e = e0 + threadIdx.x; e < e1; e += 256)
        atomicAdd(&cnt[dst[e] >> BSHIFT], 1);
    __syncthreads();
    for (int i = threadIdx.x; i < nbuck; i += 256) H[i * NWG + g] = cnt[i];
}

// ---------------- 2-level exclusive scan over PADDED counts ----------------
__global__ __launch_bounds__(1024) void scan_a(const int* __restrict__ in,
                                               int* __restrict__ out,
                                               int* __restrict__ bsums, int n) {
    __shared__ int sm[1024];
    int i = blockIdx.x * 1024 + threadIdx.x;
    int raw = (i < n) ? in[i] : 0;
    int v = (raw + 15) & ~15;          // pad to 16-int multiple
    sm[threadIdx.x] = v;
    __syncthreads();
    for (int off = 1; off < 1024; off <<= 1) {
        int t = (threadIdx.x >= off) ? sm[threadIdx.x - off] : 0;
        __syncthreads();
        sm[threadIdx.x] += t;
        __syncthreads();
    }
    if (i < n) out[i] = sm[threadIdx.x] - v;  // exclusive (pre block offset)
    if (threadIdx.x == 1023) bsums[blockIdx.x] = sm[1023];
}

__global__ __launch_bounds__(1024) void scan_b(const int* __restrict__ bsums,
                                               int* __restrict__ boffs,
                                               int* __restrict__ ptot, int NB) {
    __shared__ int sm[1024];
    int v = (threadIdx.x < NB) ? bsums[threadIdx.x] : 0;
    sm[threadIdx.x] = v;
    __syncthreads();
    for (int off = 1; off < 1024; off <<= 1) {
        int t = (threadIdx.x >= off) ? sm[threadIdx.x - off] : 0;
        __syncthreads();
        sm[threadIdx.x] += t;
        __syncthreads();
    }
    if (threadIdx.x < NB) boffs[threadIdx.x] = sm[threadIdx.x] - v;
    if (threadIdx.x == NB - 1) ptot[0] = sm[threadIdx.x];  // padded grand total
}

// ---------------- K3: LDS-staged binned append (full-line flush) -----------
// Phase 1: scatter this WG's chunk into a compact LDS image laid out as the
// concatenation of its pad16 bucket segments (pre-filled with SENT).
// Phase 2: copy LDS segments -> global as aligned dwordx4 stores; every 64B
// HBM line is written fully, once, by one WG. 16 buckets concurrent.
__global__ __launch_bounds__(256) void k3_bin(const int* __restrict__ src,
                                              const int* __restrict__ dst,
                                              const int* __restrict__ H,
                                              const int* __restrict__ O,
                                              const int* __restrict__ boffs,
                                              int* __restrict__ packed,
                                              int E, int chunk, int nbuck) {
    __shared__ int stage[SCAP];
    __shared__ int lcur[512];   // scan workspace -> exclusive local offsets
    __shared__ int lfill[512];  // atomic fill cursors (local)
    __shared__ int gbase[512];  // global segment bases
    const int g = blockIdx.x;
    const int t = threadIdx.x;

    for (int i = t; i < SCAP; i += 256) stage[i] = SENT;
    for (int i = t; i < 512; i += 256) {
        int c = (i < nbuck) ? H[i * NWG + g] : 0;
        gbase[i] = c;                      // stash raw count temporarily
        lcur[i] = (c + 15) & ~15;          // padded count for local scan
    }
    __syncthreads();
    // Hillis-Steele inclusive scan over 512 entries, 2 per thread
    for (int off = 1; off < 512; off <<= 1) {
        const int i0 = t, i1 = t + 256;
        const int v0 = (i0 >= off) ? lcur[i0 - off] : 0;
        const int v1 = (i1 >= off) ? lcur[i1 - off] : 0;
        __syncthreads();
        lcur[i0] += v0;
        lcur[i1] += v1;
        __syncthreads();
    }
    for (int i = t; i < nbuck; i += 256) {
        const int pad = (gbase[i] + 15) & ~15;
        const int excl = lcur[i] - pad;    // exclusive padded prefix
        lcur[i] = excl;
        lfill[i] = excl;
        const int fi = i * NWG + g;
        gbase[i] = O[fi] + boffs[fi >> 10];
    }
    __syncthreads();

    // phase 1: scatter into LDS stage
    const int e0 = g * chunk;
    const int e1 = min(E, e0 + chunk);
    for (int e = e0 + t; e < e1; e += 256) {
        const int d = dst[e];
        const int b = d >> BSHIFT;
        const int pos = atomicAdd(&lfill[b], 1);
        stage[pos] = ((d & (NPB - 1)) << 17) | src[e];
    }
    __syncthreads();

    // phase 2: full-line flush; 16 buckets concurrent, 16 lanes per bucket
    const int sub = t >> 4;        // 0..15: concurrent bucket slot
    const int l16 = t & 15;
    for (int b = sub; b < nbuck; b += 16) {
        const int lo = lcur[b];
        const int n4 = ((lfill[b] - lo + 15) & ~15) >> 2;
        int* __restrict__ gp = packed + gbase[b];
        for (int k = l16; k < n4; k += 16) {
            const int4 v = *(const int4*)&stage[lo + 4 * k];
            *(int4*)&gp[4 * k] = v;
        }
    }
}

// ---------------- K4: within-bucket sort (LDS-staged, in-place) ------------
__global__ __launch_bounds__(256) void k4_local_sort(const int* __restrict__ O,
                                                     const int* __restrict__ boffs,
                                                     const int* __restrict__ ptot,
                                                     int* __restrict__ packed,
                                                     int* __restrict__ rowbeg,
                                                     int* __restrict__ rowend,
                                                     float* __restrict__ dinv,
                                                     int N, int nbuck) {
    __shared__ int sseg[SEGCAP];
    __shared__ int lcnt[NPB];
    __shared__ int s[NPB];
    __shared__ int lpos[NPB];
    const int b = blockIdx.x;
    const int ib = b * NWG;
    const int segbeg = O[ib] + boffs[ib >> 10];
    int segend;
    if (b + 1 < nbuck) {
        const int ie = (b + 1) * NWG;
        segend = O[ie] + boffs[ie >> 10];
    } else {
        segend = ptot[0];
    }
    int seglen = segend - segbeg;
    if (seglen > SEGCAP) seglen = SEGCAP;  // safety clamp; never triggers here
    const int n0 = b << BSHIFT;
    const int ncnt = min(N - n0, NPB);
    const int t = threadIdx.x;

    lcnt[t] = 0;
    // coalesced load of the whole segment (incl. sentinels) into LDS
    for (int i = t; i < seglen; i += 256) sseg[i] = packed[segbeg + i];
    __syncthreads();
    for (int i = t; i < seglen; i += 256) {
        const int p = sseg[i];
        if (p >= 0) atomicAdd(&lcnt[(p >> 17) & (NPB - 1)], 1);
    }
    __syncthreads();
    // inclusive scan of lcnt into s (NPB == blockDim, unguarded)
    s[t] = lcnt[t];
    __syncthreads();
    for (int off = 1; off < NPB; off <<= 1) {
        int v = (t >= off) ? s[t - off] : 0;
        __syncthreads();
        s[t] += v;
        __syncthreads();
    }
    const int excl = s[t] - lcnt[t];
    lpos[t] = excl;
    if (t < ncnt) {
        rowbeg[n0 + t] = segbeg + excl;
        rowend[n0 + t] = segbeg + s[t];
        dinv[n0 + t] = rsqrtf((float)(lcnt[t] + 1));  // +1 self-loop
    }
    __syncthreads();
    // scatter compact col values back into packed[] (reads all from LDS)
    for (int i = t; i < seglen; i += 256) {
        const int p = sseg[i];
        if (p >= 0) {
            const int dl = (p >> 17) & (NPB - 1);
            const int pos = segbeg + atomicAdd(&lpos[dl], 1);
            packed[pos] = p & 0x1FFFF;
        }
    }
}

// ---------------- h2 = bf16((x @ W) * dinv[row])  via bf16x3 MFMA ----------------
__global__ __launch_bounds__(512) void gemm_mfma_kernel(const float* __restrict__ x,
                                                        const float* __restrict__ W,
                                                        const float* __restrict__ dinv,
                                                        unsigned short* __restrict__ h2,
                                                        int N) {
    __shared__ unsigned short Whi[COUT * WPAD];
    __shared__ unsigned short Wlo[COUT * WPAD];
    for (int i = threadIdx.x; i < CIN * COUT; i += 512) {
        int k = i >> 6, c = i & 63;
        float w = W[i];
        unsigned u = fbits(w);
        unsigned short h = (unsigned short)(u >> 16);  // trunc split
        float r = w - bbits(u & 0xFFFF0000u);
        Whi[c * WPAD + k] = h;
        Wlo[c * WPAD + k] = (unsigned short)(fbits(r) >> 16);
    }
    __syncthreads();

    const int lane = threadIdx.x & 63;
    const int wave = threadIdx.x >> 6;
    const int m = lane & 15;
    const int q = lane >> 4;
    const int row0 = blockIdx.x * 256 + wave * 32;

    int ar0 = row0 + m;
    int ar1 = row0 + 16 + m;
    if (ar0 >= N) ar0 = N - 1;  // clamp; stores are guarded
    if (ar1 >= N) ar1 = N - 1;
    const float* __restrict__ xr0 = x + (size_t)ar0 * CIN + q * 8;
    const float* __restrict__ xr1 = x + (size_t)ar1 * CIN + q * 8;

    floatx4 acc0[4] = {floatx4{0,0,0,0}, floatx4{0,0,0,0}, floatx4{0,0,0,0}, floatx4{0,0,0,0}};
    floatx4 acc1[4] = {floatx4{0,0,0,0}, floatx4{0,0,0,0}, floatx4{0,0,0,0}, floatx4{0,0,0,0}};

#pragma unroll
    for (int kc = 0; kc < 8; ++kc) {
        floatx4 a00 = *(const floatx4*)(xr0 + kc * 32);
        floatx4 a01 = *(const floatx4*)(xr0 + kc * 32 + 4);
        floatx4 a10 = *(const floatx4*)(xr1 + kc * 32);
        floatx4 a11 = *(const floatx4*)(xr1 + kc * 32 + 4);
        short8 ahi0, alo0, ahi1, alo1;
        split8(a00, a01, ahi0, alo0);
        split8(a10, a11, ahi1, alo1);
        const int kb = kc * 32 + q * 8;
#pragma unroll
        for (int ct = 0; ct < 4; ++ct) {
            const int c = ct * 16 + m;
            short8 bhi = *(const short8*)&Whi[c * WPAD + kb];
            short8 blo = *(const short8*)&Wlo[c * WPAD + kb];
            acc0[ct] = __builtin_amdgcn_mfma_f32_16x16x32_bf16(ahi0, bhi, acc0[ct], 0, 0, 0);
            acc0[ct] = __builtin_amdgcn_mfma_f32_16x16x32_bf16(ahi0, blo, acc0[ct], 0, 0, 0);
            acc0[ct] = __builtin_amdgcn_mfma_f32_16x16x32_bf16(alo0, bhi, acc0[ct], 0, 0, 0);
            acc1[ct] = __builtin_amdgcn_mfma_f32_16x16x32_bf16(ahi1, bhi, acc1[ct], 0, 0, 0);
            acc1[ct] = __builtin_amdgcn_mfma_f32_16x16x32_bf16(ahi1, blo, acc1[ct], 0, 0, 0);
            acc1[ct] = __builtin_amdgcn_mfma_f32_16x16x32_bf16(alo1, bhi, acc1[ct], 0, 0, 0);
        }
    }

    // C/D layout: col = lane&15 (= m), row = q*4 + reg
#pragma unroll
    for (int t = 0; t < 2; ++t) {
#pragma unroll
        for (int r = 0; r < 4; ++r) {
            const int row = row0 + t * 16 + q * 4 + r;
            if (row < N) {
                const float dv = dinv[row];
                unsigned short* __restrict__ op = h2 + (size_t)row * COUT;
#pragma unroll
                for (int ct = 0; ct < 4; ++ct) {
                    float v = (t == 0) ? acc0[ct][r] : acc1[ct][r];
                    op[ct * 16 + m] = f2bf(v * dv);
                }
            }
        }
    }
}

// ---------------- pull-gather: one wave per node, lane = channel PAIR ----------------
// Main loop: 32 edges/iter (16 h2 rows in flight per wave-half) + col prefetch.
__global__ __launch_bounds__(256) void gather_kernel(const unsigned short* __restrict__ h2,
                                                     const int* __restrict__ rowbeg,
                                                     const int* __restrict__ rowend,
                                                     const int* __restrict__ col,
                                                     const float* __restrict__ dinv,
                                                     const float* __restrict__ b,
                                                     float* __restrict__ out, int N) {
    const int lane = threadIdx.x & 63;
    const int h = lane >> 5;
    const int c = lane & 31;
    const int node = blockIdx.x * 4 + (threadIdx.x >> 6);
    if (node >= N) return;
    const unsigned* __restrict__ h2u = (const unsigned*)h2;
    const int p0 = rowbeg[node];
    const int p1 = rowend[node];
    float a0 = 0.f, a1 = 0.f;
    int p = p0;

    const int nmain = (p1 - p0) >> 5;   // 32-edge iterations
    if (nmain > 0) {
        int e[16];
#pragma unroll
        for (int i = 0; i < 16; ++i) e[i] = col[p + 2 * i + h];
        for (int it = 0; it < nmain; ++it) {
            unsigned u[16];
#pragma unroll
            for (int i = 0; i < 16; ++i) u[i] = h2u[(size_t)e[i] * 32 + c];
            const int pn = p + 32;
            if (it + 1 < nmain) {  // prefetch next col group while h2 loads fly
#pragma unroll
                for (int i = 0; i < 16; ++i) e[i] = col[pn + 2 * i + h];
            }
            // paired-tree accumulate (4 partials for ILP)
            float s00 = 0.f, s01 = 0.f, s02 = 0.f, s03 = 0.f;
            float s10 = 0.f, s11 = 0.f, s12 = 0.f, s13 = 0.f;
#pragma unroll
            for (int i = 0; i < 4; ++i) {
                s00 += bbits(u[i] << 16);
                s01 += bbits(u[4 + i] << 16);
                s02 += bbits(u[8 + i] << 16);
                s03 += bbits(u[12 + i] << 16);
                s10 += bbits(u[i] & 0xFFFF0000u);
                s11 += bbits(u[4 + i] & 0xFFFF0000u);
                s12 += bbits(u[8 + i] & 0xFFFF0000u);
                s13 += bbits(u[12 + i] & 0xFFFF0000u);
            }
            a0 += (s00 + s01) + (s02 + s03);
            a1 += (s10 + s11) + (s12 + s13);
            p = pn;
        }
    }
    // 16-edge leftover (at most once)
    if (p + 15 < p1) {
        const int e0 = col[p + h],      e1 = col[p + 2 + h];
        const int e2 = col[p + 4 + h],  e3 = col[p + 6 + h];
        const int e4 = col[p + 8 + h],  e5 = col[p + 10 + h];
        const int e6 = col[p + 12 + h], e7 = col[p + 14 + h];
        const unsigned u0 = h2u[(size_t)e0 * 32 + c];
        const unsigned u1 = h2u[(size_t)e1 * 32 + c];
        const unsigned u2 = h2u[(size_t)e2 * 32 + c];
        const unsigned u3 = h2u[(size_t)e3 * 32 + c];
        const unsigned u4 = h2u[(size_t)e4 * 32 + c];
        const unsigned u5 = h2u[(size_t)e5 * 32 + c];
        const unsigned u6 = h2u[(size_t)e6 * 32 + c];
        const unsigned u7 = h2u[(size_t)e7 * 32 + c];
        a0 += ((bbits(u0 << 16) + bbits(u1 << 16)) + (bbits(u2 << 16) + bbits(u3 << 16))) +
              ((bbits(u4 << 16) + bbits(u5 << 16)) + (bbits(u6 << 16) + bbits(u7 << 16)));
        a1 += ((bbits(u0 & 0xFFFF0000u) + bbits(u1 & 0xFFFF0000u)) +
               (bbits(u2 & 0xFFFF0000u) + bbits(u3 & 0xFFFF0000u))) +
              ((bbits(u4 & 0xFFFF0000u) + bbits(u5 & 0xFFFF0000u)) +
               (bbits(u6 & 0xFFFF0000u) + bbits(u7 & 0xFFFF0000u)));
        p += 16;
    }
    // 8-edge leftover (at most once)
    for (; p + 7 < p1; p += 8) {
        const int e0 = col[p + h],     e1 = col[p + 2 + h];
        const int e2 = col[p + 4 + h], e3 = col[p + 6 + h];
        const unsigned u0 = h2u[(size_t)e0 * 32 + c];
        const unsigned u1 = h2u[(size_t)e1 * 32 + c];
        const unsigned u2 = h2u[(size_t)e2 * 32 + c];
        const unsigned u3 = h2u[(size_t)e3 * 32 + c];
        a0 += (bbits(u0 << 16) + bbits(u1 << 16)) + (bbits(u2 << 16) + bbits(u3 << 16));
        a1 += (bbits(u0 & 0xFFFF0000u) + bbits(u1 & 0xFFFF0000u)) +
              (bbits(u2 & 0xFFFF0000u) + bbits(u3 & 0xFFFF0000u));
    }
    for (; p + 1 < p1; p += 2) {
        const int e = col[p + h];
        const unsigned u = h2u[(size_t)e * 32 + c];
        a0 += bbits(u << 16);
        a1 += bbits(u & 0xFFFF0000u);
    }
    if (p < p1 && h == 0) {  // odd leftover edge: half 0 only
        const unsigned u = h2u[(size_t)col[p] * 32 + c];
        a0 += bbits(u << 16);
        a1 += bbits(u & 0xFFFF0000u);
    }
    // combine edge-parity halves
    a0 += __shfl_xor(a0, 32, 64);
    a1 += __shfl_xor(a1, 32, 64);
    if (h == 0) {
        const unsigned su = h2u[(size_t)node * 32 + c];  // self-loop term
        const float dv = dinv[node];
        const float2 bb = ((const float2*)b)[c];
        float2 o;
        o.x = (a0 + bbits(su << 16)) * dv + bb.x;
        o.y = (a1 + bbits(su & 0xFFFF0000u)) * dv + bb.y;
        ((float2*)out)[(size_t)node * 32 + c] = o;
    }
}

// ---------------- launch ----------------
extern "C" void kernel_launch(void* const* d_in, const int* in_sizes, int n_in,
                              void* d_out, int out_size, void* d_ws, size_t ws_size,
                              hipStream_t stream) {
    const float* x = (const float*)d_in[0];
    const int* ei = (const int*)d_in[1];
    const float* W = (const float*)d_in[2];
    const float* b = (const float*)d_in[3];
    float* out = (float*)d_out;

    const int N = in_sizes[0] / CIN;
    const int E = in_sizes[1] / 2;
    const int* src = ei;
    const int* dst = ei + E;

    const int nbuck = (N + NPB - 1) >> BSHIFT;        // 391
    const int nH = nbuck * NWG;                        // 200192
    const int chunk = (E + NWG - 1) / NWG;             // 6250
    const int NBs = (nH + 1023) / 1024;                // 196 (must be <= 1024)
    const int padcap = E + 16 * nH;                    // worst-case padded extent

    // workspace layout (256 B aligned chunks); total ~41.5 MB
    auto align_up = [](size_t v) { return (v + 255) & ~(size_t)255; };
    char* ws = (char*)d_ws;
    size_t off = 0;
    int* H = (int*)(ws + off);        off = align_up(off + (size_t)nH * 4);
    int* O = (int*)(ws + off);        off = align_up(off + (size_t)nH * 4);
    int* bsums = (int*)(ws + off);    off = align_up(off + (size_t)NBs * 4);
    int* boffs = (int*)(ws + off);    off = align_up(off + (size_t)NBs * 4);
    int* ptot = (int*)(ws + off);     off = align_up(off + 4);
    int* rowbeg = (int*)(ws + off);   off = align_up(off + (size_t)N * 4);
    int* rowend = (int*)(ws + off);   off = align_up(off + (size_t)N * 4);
    float* dinv = (float*)(ws + off); off = align_up(off + (size_t)N * 4);
    int* packed = (int*)(ws + off);   off = align_up(off + (size_t)padcap * 4);
    unsigned short* h2 = (unsigned short*)(ws + off);
    off = align_up(off + (size_t)N * COUT * 2);
    (void)ws_size;

    // 1. per-workgroup bucket histogram
    k1_bucket_hist<<<NWG, 256, 0, stream>>>(dst, H, E, chunk, nbuck);
    // 2-3. exclusive scan of line-padded H -> 64B-aligned private ranges O
    scan_a<<<NBs, 1024, 0, stream>>>(H, O, bsums, nH);
    scan_b<<<1, 1024, 0, stream>>>(bsums, boffs, ptot, NBs);
    // 4. LDS-staged binned append, full-line flush (16-bucket-wide)
    k3_bin<<<NWG, 256, 0, stream>>>(src, dst, H, O, boffs, packed, E, chunk, nbuck);
    // 5. within-bucket counting sort, LDS-staged, in-place -> rowbeg/rowend, dinv
    k4_local_sort<<<nbuck, 256, 0, stream>>>(O, boffs, ptot, packed, rowbeg, rowend, dinv, N, nbuck);
    // 6. projection h2 = bf16((x@W)*dinv) via bf16x3 MFMA, 32 rows/wave
    gemm_mfma_kernel<<<(N + 255) / 256, 512, 0, stream>>>(x, W, dinv, h2, N);
    // 7. pull-gather + bias (32-edge pipelined main loop, col prefetch; col==packed)
    gather_kernel<<<(N + 3) / 4, 256, 0, stream>>>(h2, rowbeg, rowend, packed, dinv, b, out, N);
}

// Round 10
// 306.771 us; speedup vs baseline: 1.2629x; 1.0704x over previous
//
#include <hip/hip_runtime.h>
#include <hip/hip_bf16.h>

#define CIN 256
#define COUT 64
#define WPAD 264       // padded K stride for transposed W in LDS
#define BSHIFT 8       // nodes per bucket = 256
#define NPB 256        // nodes per bucket
#define NWG 512        // workgroups for binning passes (2 blocks/CU)
#define SENT ((int)0x80000000u)  // sentinel pad word in packed[]
#define SEGCAP 13312   // k4 LDS staging capacity for one bucket segment (ints)
#define SCAP 12160     // k3 LDS stage capacity (>= chunk 6250 + 15*nbuck 391)

typedef __attribute__((ext_vector_type(8))) short short8;
typedef __attribute__((ext_vector_type(4))) float floatx4;

static __device__ __forceinline__ unsigned int fbits(float f) {
    return __builtin_bit_cast(unsigned int, f);
}
static __device__ __forceinline__ float bbits(unsigned int u) {
    return __builtin_bit_cast(float, u);
}
// RTN fp32->bf16 (gemm epilogue only)
static __device__ __forceinline__ unsigned short f2bf(float f) {
    unsigned u = fbits(f);
    return (unsigned short)((u + 0x7FFFu + ((u >> 16) & 1u)) >> 16);
}

// truncation-split of 8 fp32 into bf16 hi/lo short8 fragments (v_perm packing).
union U8 { short8 s; unsigned int u[4]; };
static __device__ __forceinline__ void split8(floatx4 a0, floatx4 a1,
                                              short8& hi, short8& lo) {
    float f[8] = {a0[0], a0[1], a0[2], a0[3], a1[0], a1[1], a1[2], a1[3]};
    U8 H, L;
#pragma unroll
    for (int j = 0; j < 4; ++j) {
        unsigned u0 = fbits(f[2 * j]);
        unsigned u1 = fbits(f[2 * j + 1]);
        H.u[j] = __builtin_amdgcn_perm(u1, u0, 0x07060302u);
        float r0 = f[2 * j] - bbits(u0 & 0xFFFF0000u);
        float r1 = f[2 * j + 1] - bbits(u1 & 0xFFFF0000u);
        L.u[j] = __builtin_amdgcn_perm(fbits(r1), fbits(r0), 0x07060302u);
    }
    hi = H.s;
    lo = L.s;
}

// ---------------- K1: per-workgroup bucket histogram (1024 thr, 32 waves/CU) ----
__global__ __launch_bounds__(1024) void k1_bucket_hist(const int* __restrict__ dst,
                                                       int* __restrict__ H,
                                                       int E, int chunk, int nbuck) {
    __shared__ int cnt[512];
    for (int i = threadIdx.x; i < 512; i += 1024) cnt[i] = 0;
    __syncthreads();
    const int g = blockIdx.x;
    const int e0 = g * chunk;
    const int e1 = min(E, e0 + chunk);
    for (int e = e0 + threadIdx.x; e < e1; e += 1024)
        atomicAdd(&cnt[dst[e] >> BSHIFT], 1);
    __syncthreads();
    for (int i = threadIdx.x; i < nbuck; i += 1024) H[i * NWG + g] = cnt[i];
}

// ---------------- 2-level exclusive scan over PADDED counts ----------------
__global__ __launch_bounds__(1024) void scan_a(const int* __restrict__ in,
                                               int* __restrict__ out,
                                               int* __restrict__ bsums, int n) {
    __shared__ int sm[1024];
    int i = blockIdx.x * 1024 + threadIdx.x;
    int raw = (i < n) ? in[i] : 0;
    int v = (raw + 15) & ~15;          // pad to 16-int multiple
    sm[threadIdx.x] = v;
    __syncthreads();
    for (int off = 1; off < 1024; off <<= 1) {
        int t = (threadIdx.x >= off) ? sm[threadIdx.x - off] : 0;
        __syncthreads();
        sm[threadIdx.x] += t;
        __syncthreads();
    }
    if (i < n) out[i] = sm[threadIdx.x] - v;  // exclusive (pre block offset)
    if (threadIdx.x == 1023) bsums[blockIdx.x] = sm[1023];
}

__global__ __launch_bounds__(1024) void scan_b(const int* __restrict__ bsums,
                                               int* __restrict__ boffs,
                                               int* __restrict__ ptot, int NB) {
    __shared__ int sm[1024];
    int v = (threadIdx.x < NB) ? bsums[threadIdx.x] : 0;
    sm[threadIdx.x] = v;
    __syncthreads();
    for (int off = 1; off < 1024; off <<= 1) {
        int t = (threadIdx.x >= off) ? sm[threadIdx.x - off] : 0;
        __syncthreads();
        sm[threadIdx.x] += t;
        __syncthreads();
    }
    if (threadIdx.x < NB) boffs[threadIdx.x] = sm[threadIdx.x] - v;
    if (threadIdx.x == NB - 1) ptot[0] = sm[threadIdx.x];  // padded grand total
}

// ---------------- K3: LDS-staged binned append (full-line flush, 512 thr) ---
// Phase 1: scatter this WG's chunk into a compact LDS image laid out as the
// concatenation of its pad16 bucket segments (pre-filled with SENT).
// Phase 2: copy LDS segments -> global as aligned dwordx4 stores; every 64B
// HBM line is written fully, once, by one WG. 32 buckets concurrent.
__global__ __launch_bounds__(512) void k3_bin(const int* __restrict__ src,
                                              const int* __restrict__ dst,
                                              const int* __restrict__ H,
                                              const int* __restrict__ O,
                                              const int* __restrict__ boffs,
                                              int* __restrict__ packed,
                                              int E, int chunk, int nbuck) {
    __shared__ int stage[SCAP];
    __shared__ int lcur[512];   // scan workspace -> exclusive local offsets
    __shared__ int lfill[512];  // atomic fill cursors (local)
    __shared__ int gbase[512];  // global segment bases
    const int g = blockIdx.x;
    const int t = threadIdx.x;

    for (int i = t; i < SCAP; i += 512) stage[i] = SENT;
    {
        const int i = t;  // 512 threads cover 512 entries exactly
        int c = (i < nbuck) ? H[i * NWG + g] : 0;
        gbase[i] = c;                      // stash raw count temporarily
        lcur[i] = (c + 15) & ~15;          // padded count for local scan
    }
    __syncthreads();
    // Hillis-Steele inclusive scan over 512 entries, 1 per thread
    for (int off = 1; off < 512; off <<= 1) {
        const int v = (t >= off) ? lcur[t - off] : 0;
        __syncthreads();
        lcur[t] += v;
        __syncthreads();
    }
    if (t < nbuck) {
        const int pad = (gbase[t] + 15) & ~15;
        const int excl = lcur[t] - pad;    // exclusive padded prefix
        lcur[t] = excl;
        lfill[t] = excl;
        const int fi = t * NWG + g;
        gbase[t] = O[fi] + boffs[fi >> 10];
    }
    __syncthreads();

    // phase 1: scatter into LDS stage
    const int e0 = g * chunk;
    const int e1 = min(E, e0 + chunk);
    for (int e = e0 + t; e < e1; e += 512) {
        const int d = dst[e];
        const int b = d >> BSHIFT;
        const int pos = atomicAdd(&lfill[b], 1);
        stage[pos] = ((d & (NPB - 1)) << 17) | src[e];
    }
    __syncthreads();

    // phase 2: full-line flush; 32 buckets concurrent, 16 lanes per bucket
    const int sub = t >> 4;        // 0..31: concurrent bucket slot
    const int l16 = t & 15;
    for (int b = sub; b < nbuck; b += 32) {
        const int lo = lcur[b];
        const int n4 = ((lfill[b] - lo + 15) & ~15) >> 2;
        int* __restrict__ gp = packed + gbase[b];
        for (int k = l16; k < n4; k += 16) {
            const int4 v = *(const int4*)&stage[lo + 4 * k];
            *(int4*)&gp[4 * k] = v;
        }
    }
}

// ---------------- K4: within-bucket sort (LDS-staged, in-place, 512 thr) ----
__global__ __launch_bounds__(512) void k4_local_sort(const int* __restrict__ O,
                                                     const int* __restrict__ boffs,
                                                     const int* __restrict__ ptot,
                                                     int* __restrict__ packed,
                                                     int* __restrict__ rowbeg,
                                                     int* __restrict__ rowend,
                                                     float* __restrict__ dinv,
                                                     int N, int nbuck) {
    __shared__ int sseg[SEGCAP];
    __shared__ int lcnt[NPB];
    __shared__ int s[NPB];
    __shared__ int lpos[NPB];
    const int b = blockIdx.x;
    const int ib = b * NWG;
    const int segbeg = O[ib] + boffs[ib >> 10];
    int segend;
    if (b + 1 < nbuck) {
        const int ie = (b + 1) * NWG;
        segend = O[ie] + boffs[ie >> 10];
    } else {
        segend = ptot[0];
    }
    int seglen = segend - segbeg;
    if (seglen > SEGCAP) seglen = SEGCAP;  // safety clamp; never triggers here
    const int n0 = b << BSHIFT;
    const int ncnt = min(N - n0, NPB);
    const int t = threadIdx.x;

    if (t < NPB) lcnt[t] = 0;
    // coalesced load of the whole segment (incl. sentinels) into LDS
    for (int i = t; i < seglen; i += 512) sseg[i] = packed[segbeg + i];
    __syncthreads();
    for (int i = t; i < seglen; i += 512) {
        const int p = sseg[i];
        if (p >= 0) atomicAdd(&lcnt[(p >> 17) & (NPB - 1)], 1);
    }
    __syncthreads();
    // inclusive scan of lcnt into s (first NPB threads; barriers wave-uniform)
    if (t < NPB) s[t] = lcnt[t];
    __syncthreads();
    for (int off = 1; off < NPB; off <<= 1) {
        int v = 0;
        if (t < NPB && t >= off) v = s[t - off];
        __syncthreads();
        if (t < NPB) s[t] += v;
        __syncthreads();
    }
    if (t < NPB) {
        const int excl = s[t] - lcnt[t];
        lpos[t] = excl;
        if (t < ncnt) {
            rowbeg[n0 + t] = segbeg + excl;
            rowend[n0 + t] = segbeg + s[t];
            dinv[n0 + t] = rsqrtf((float)(lcnt[t] + 1));  // +1 self-loop
        }
    }
    __syncthreads();
    // scatter compact col values back into packed[] (reads all from LDS)
    for (int i = t; i < seglen; i += 512) {
        const int p = sseg[i];
        if (p >= 0) {
            const int dl = (p >> 17) & (NPB - 1);
            const int pos = segbeg + atomicAdd(&lpos[dl], 1);
            packed[pos] = p & 0x1FFFF;
        }
    }
}

// ---------------- h2 = bf16((x @ W) * dinv[row])  via bf16x3 MFMA ----------------
__global__ __launch_bounds__(512) void gemm_mfma_kernel(const float* __restrict__ x,
                                                        const float* __restrict__ W,
                                                        const float* __restrict__ dinv,
                                                        unsigned short* __restrict__ h2,
                                                        int N) {
    __shared__ unsigned short Whi[COUT * WPAD];
    __shared__ unsigned short Wlo[COUT * WPAD];
    for (int i = threadIdx.x; i < CIN * COUT; i += 512) {
        int k = i >> 6, c = i & 63;
        float w = W[i];
        unsigned u = fbits(w);
        unsigned short h = (unsigned short)(u >> 16);  // trunc split
        float r = w - bbits(u & 0xFFFF0000u);
        Whi[c * WPAD + k] = h;
        Wlo[c * WPAD + k] = (unsigned short)(fbits(r) >> 16);
    }
    __syncthreads();

    const int lane = threadIdx.x & 63;
    const int wave = threadIdx.x >> 6;
    const int m = lane & 15;
    const int q = lane >> 4;
    const int row0 = blockIdx.x * 256 + wave * 32;

    int ar0 = row0 + m;
    int ar1 = row0 + 16 + m;
    if (ar0 >= N) ar0 = N - 1;  // clamp; stores are guarded
    if (ar1 >= N) ar1 = N - 1;
    const float* __restrict__ xr0 = x + (size_t)ar0 * CIN + q * 8;
    const float* __restrict__ xr1 = x + (size_t)ar1 * CIN + q * 8;

    floatx4 acc0[4] = {floatx4{0,0,0,0}, floatx4{0,0,0,0}, floatx4{0,0,0,0}, floatx4{0,0,0,0}};
    floatx4 acc1[4] = {floatx4{0,0,0,0}, floatx4{0,0,0,0}, floatx4{0,0,0,0}, floatx4{0,0,0,0}};

#pragma unroll
    for (int kc = 0; kc < 8; ++kc) {
        floatx4 a00 = *(const floatx4*)(xr0 + kc * 32);
        floatx4 a01 = *(const floatx4*)(xr0 + kc * 32 + 4);
        floatx4 a10 = *(const floatx4*)(xr1 + kc * 32);
        floatx4 a11 = *(const floatx4*)(xr1 + kc * 32 + 4);
        short8 ahi0, alo0, ahi1, alo1;
        split8(a00, a01, ahi0, alo0);
        split8(a10, a11, ahi1, alo1);
        const int kb = kc * 32 + q * 8;
#pragma unroll
        for (int ct = 0; ct < 4; ++ct) {
            const int c = ct * 16 + m;
            short8 bhi = *(const short8*)&Whi[c * WPAD + kb];
            short8 blo = *(const short8*)&Wlo[c * WPAD + kb];
            acc0[ct] = __builtin_amdgcn_mfma_f32_16x16x32_bf16(ahi0, bhi, acc0[ct], 0, 0, 0);
            acc0[ct] = __builtin_amdgcn_mfma_f32_16x16x32_bf16(ahi0, blo, acc0[ct], 0, 0, 0);
            acc0[ct] = __builtin_amdgcn_mfma_f32_16x16x32_bf16(alo0, bhi, acc0[ct], 0, 0, 0);
            acc1[ct] = __builtin_amdgcn_mfma_f32_16x16x32_bf16(ahi1, bhi, acc1[ct], 0, 0, 0);
            acc1[ct] = __builtin_amdgcn_mfma_f32_16x16x32_bf16(ahi1, blo, acc1[ct], 0, 0, 0);
            acc1[ct] = __builtin_amdgcn_mfma_f32_16x16x32_bf16(alo1, bhi, acc1[ct], 0, 0, 0);
        }
    }

    // C/D layout: col = lane&15 (= m), row = q*4 + reg
#pragma unroll
    for (int t = 0; t < 2; ++t) {
#pragma unroll
        for (int r = 0; r < 4; ++r) {
            const int row = row0 + t * 16 + q * 4 + r;
            if (row < N) {
                const float dv = dinv[row];
                unsigned short* __restrict__ op = h2 + (size_t)row * COUT;
#pragma unroll
                for (int ct = 0; ct < 4; ++ct) {
                    float v = (t == 0) ? acc0[ct][r] : acc1[ct][r];
                    op[ct * 16 + m] = f2bf(v * dv);
                }
            }
        }
    }
}

// ---------------- pull-gather: one wave per node, lane = channel PAIR ----------------
// Proven R7 version: 16 edges/iter (8 h2 rows in flight per half) + col prefetch.
__global__ __launch_bounds__(256) void gather_kernel(const unsigned short* __restrict__ h2,
                                                     const int* __restrict__ rowbeg,
                                                     const int* __restrict__ rowend,
                                                     const int* __restrict__ col,
                                                     const float* __restrict__ dinv,
                                                     const float* __restrict__ b,
                                                     float* __restrict__ out, int N) {
    const int lane = threadIdx.x & 63;
    const int h = lane >> 5;
    const int c = lane & 31;
    const int node = blockIdx.x * 4 + (threadIdx.x >> 6);
    if (node >= N) return;
    const unsigned* __restrict__ h2u = (const unsigned*)h2;
    const int p0 = rowbeg[node];
    const int p1 = rowend[node];
    float a0 = 0.f, a1 = 0.f;
    int p = p0;

    const int nmain = (p1 - p0) >> 4;   // 16-edge iterations
    if (nmain > 0) {
        // preload col group 0 (8 edges per half)
        int e0 = col[p + h],      e1 = col[p + 2 + h];
        int e2 = col[p + 4 + h],  e3 = col[p + 6 + h];
        int e4 = col[p + 8 + h],  e5 = col[p + 10 + h];
        int e6 = col[p + 12 + h], e7 = col[p + 14 + h];
        for (int it = 0; it < nmain; ++it) {
            const unsigned u0 = h2u[(size_t)e0 * 32 + c];
            const unsigned u1 = h2u[(size_t)e1 * 32 + c];
            const unsigned u2 = h2u[(size_t)e2 * 32 + c];
            const unsigned u3 = h2u[(size_t)e3 * 32 + c];
            const unsigned u4 = h2u[(size_t)e4 * 32 + c];
            const unsigned u5 = h2u[(size_t)e5 * 32 + c];
            const unsigned u6 = h2u[(size_t)e6 * 32 + c];
            const unsigned u7 = h2u[(size_t)e7 * 32 + c];
            const int pn = p + 16;
            if (it + 1 < nmain) {  // prefetch next col group while h2 loads fly
                e0 = col[pn + h];      e1 = col[pn + 2 + h];
                e2 = col[pn + 4 + h];  e3 = col[pn + 6 + h];
                e4 = col[pn + 8 + h];  e5 = col[pn + 10 + h];
                e6 = col[pn + 12 + h]; e7 = col[pn + 14 + h];
            }
            a0 += ((bbits(u0 << 16) + bbits(u1 << 16)) + (bbits(u2 << 16) + bbits(u3 << 16))) +
                  ((bbits(u4 << 16) + bbits(u5 << 16)) + (bbits(u6 << 16) + bbits(u7 << 16)));
            a1 += ((bbits(u0 & 0xFFFF0000u) + bbits(u1 & 0xFFFF0000u)) +
                   (bbits(u2 & 0xFFFF0000u) + bbits(u3 & 0xFFFF0000u))) +
                  ((bbits(u4 & 0xFFFF0000u) + bbits(u5 & 0xFFFF0000u)) +
                   (bbits(u6 & 0xFFFF0000u) + bbits(u7 & 0xFFFF0000u)));
            p = pn;
        }
    }
    // 8-edge leftover (runs at most once)
    for (; p + 7 < p1; p += 8) {
        const int e0 = col[p + h],     e1 = col[p + 2 + h];
        const int e2 = col[p + 4 + h], e3 = col[p + 6 + h];
        const unsigned u0 = h2u[(size_t)e0 * 32 + c];
        const unsigned u1 = h2u[(size_t)e1 * 32 + c];
        const unsigned u2 = h2u[(size_t)e2 * 32 + c];
        const unsigned u3 = h2u[(size_t)e3 * 32 + c];
        a0 += (bbits(u0 << 16) + bbits(u1 << 16)) + (bbits(u2 << 16) + bbits(u3 << 16));
        a1 += (bbits(u0 & 0xFFFF0000u) + bbits(u1 & 0xFFFF0000u)) +
              (bbits(u2 & 0xFFFF0000u) + bbits(u3 & 0xFFFF0000u));
    }
    for (; p + 1 < p1; p += 2) {
        const int e = col[p + h];
        const unsigned u = h2u[(size_t)e * 32 + c];
        a0 += bbits(u << 16);
        a1 += bbits(u & 0xFFFF0000u);
    }
    if (p < p1 && h == 0) {  // odd leftover edge: half 0 only
        const unsigned u = h2u[(size_t)col[p] * 32 + c];
        a0 += bbits(u << 16);
        a1 += bbits(u & 0xFFFF0000u);
    }
    // combine edge-parity halves
    a0 += __shfl_xor(a0, 32, 64);
    a1 += __shfl_xor(a1, 32, 64);
    if (h == 0) {
        const unsigned su = h2u[(size_t)node * 32 + c];  // self-loop term
        const float dv = dinv[node];
        const float2 bb = ((const float2*)b)[c];
        float2 o;
        o.x = (a0 + bbits(su << 16)) * dv + bb.x;
        o.y = (a1 + bbits(su & 0xFFFF0000u)) * dv + bb.y;
        ((float2*)out)[(size_t)node * 32 + c] = o;
    }
}

// ---------------- launch ----------------
extern "C" void kernel_launch(void* const* d_in, const int* in_sizes, int n_in,
                              void* d_out, int out_size, void* d_ws, size_t ws_size,
                              hipStream_t stream) {
    const float* x = (const float*)d_in[0];
    const int* ei = (const int*)d_in[1];
    const float* W = (const float*)d_in[2];
    const float* b = (const float*)d_in[3];
    float* out = (float*)d_out;

    const int N = in_sizes[0] / CIN;
    const int E = in_sizes[1] / 2;
    const int* src = ei;
    const int* dst = ei + E;

    const int nbuck = (N + NPB - 1) >> BSHIFT;        // 391
    const int nH = nbuck * NWG;                        // 200192
    const int chunk = (E + NWG - 1) / NWG;             // 6250
    const int NBs = (nH + 1023) / 1024;                // 196 (must be <= 1024)
    const int padcap = E + 16 * nH;                    // worst-case padded extent

    // workspace layout (256 B aligned chunks); total ~41.5 MB
    auto align_up = [](size_t v) { return (v + 255) & ~(size_t)255; };
    char* ws = (char*)d_ws;
    size_t off = 0;
    int* H = (int*)(ws + off);        off = align_up(off + (size_t)nH * 4);
    int* O = (int*)(ws + off);        off = align_up(off + (size_t)nH * 4);
    int* bsums = (int*)(ws + off);    off = align_up(off + (size_t)NBs * 4);
    int* boffs = (int*)(ws + off);    off = align_up(off + (size_t)NBs * 4);
    int* ptot = (int*)(ws + off);     off = align_up(off + 4);
    int* rowbeg = (int*)(ws + off);   off = align_up(off + (size_t)N * 4);
    int* rowend = (int*)(ws + off);   off = align_up(off + (size_t)N * 4);
    float* dinv = (float*)(ws + off); off = align_up(off + (size_t)N * 4);
    int* packed = (int*)(ws + off);   off = align_up(off + (size_t)padcap * 4);
    unsigned short* h2 = (unsigned short*)(ws + off);
    off = align_up(off + (size_t)N * COUT * 2);
    (void)ws_size;

    // 1. per-workgroup bucket histogram (1024 thr -> 32 waves/CU)
    k1_bucket_hist<<<NWG, 1024, 0, stream>>>(dst, H, E, chunk, nbuck);
    // 2-3. exclusive scan of line-padded H -> 64B-aligned private ranges O
    scan_a<<<NBs, 1024, 0, stream>>>(H, O, bsums, nH);
    scan_b<<<1, 1024, 0, stream>>>(bsums, boffs, ptot, NBs);
    // 4. LDS-staged binned append, full-line flush (512 thr -> 16 waves/CU)
    k3_bin<<<NWG, 512, 0, stream>>>(src, dst, H, O, boffs, packed, E, chunk, nbuck);
    // 5. within-bucket counting sort, LDS-staged, in-place (512 thr)
    k4_local_sort<<<nbuck, 512, 0, stream>>>(O, boffs, ptot, packed, rowbeg, rowend, dinv, N, nbuck);
    // 6. projection h2 = bf16((x@W)*dinv) via bf16x3 MFMA, 32 rows/wave
    gemm_mfma_kernel<<<(N + 255) / 256, 512, 0, stream>>>(x, W, dinv, h2, N);
    // 7. pull-gather + bias (16-edge pipelined main loop, col prefetch; col==packed)
    gather_kernel<<<(N + 3) / 4, 256, 0, stream>>>(h2, rowbeg, rowend, packed, dinv, b, out, N);
}

// Round 11
// 295.861 us; speedup vs baseline: 1.3095x; 1.0369x over previous
//
#include <hip/hip_runtime.h>
#include <hip/hip_bf16.h>

#define CIN 256
#define COUT 64
#define WPAD 264       // padded K stride for transposed W in LDS
#define BSHIFT 8       // nodes per bucket = 256
#define NPB 256        // nodes per bucket
#define NWG 512        // workgroups for the binning pass
#define SENT ((int)0x80000000u)  // sentinel pad word in packed[]
#define SEGCAP 13312   // k4 LDS staging capacity for one bucket segment (ints)
#define CAP 13312      // per-bucket packed region (ints); 64B multiple; ==SEGCAP
#define NBK 392        // static array bound for buckets (nbuck = 391)
#define CELL 36        // per-(wg,bucket) LDS cell (ints); 392*36*4 = 56.4 KB

typedef __attribute__((ext_vector_type(8))) short short8;
typedef __attribute__((ext_vector_type(4))) float floatx4;

static __device__ __forceinline__ unsigned int fbits(float f) {
    return __builtin_bit_cast(unsigned int, f);
}
static __device__ __forceinline__ float bbits(unsigned int u) {
    return __builtin_bit_cast(float, u);
}
// RTN fp32->bf16 (gemm epilogue only)
static __device__ __forceinline__ unsigned short f2bf(float f) {
    unsigned u = fbits(f);
    return (unsigned short)((u + 0x7FFFu + ((u >> 16) & 1u)) >> 16);
}

// truncation-split of 8 fp32 into bf16 hi/lo short8 fragments (v_perm packing).
union U8 { short8 s; unsigned int u[4]; };
static __device__ __forceinline__ void split8(floatx4 a0, floatx4 a1,
                                              short8& hi, short8& lo) {
    float f[8] = {a0[0], a0[1], a0[2], a0[3], a1[0], a1[1], a1[2], a1[3]};
    U8 H, L;
#pragma unroll
    for (int j = 0; j < 4; ++j) {
        unsigned u0 = fbits(f[2 * j]);
        unsigned u1 = fbits(f[2 * j + 1]);
        H.u[j] = __builtin_amdgcn_perm(u1, u0, 0x07060302u);
        float r0 = f[2 * j] - bbits(u0 & 0xFFFF0000u);
        float r1 = f[2 * j + 1] - bbits(u1 & 0xFFFF0000u);
        L.u[j] = __builtin_amdgcn_perm(fbits(r1), fbits(r0), 0x07060302u);
    }
    hi = H.s;
    lo = L.s;
}

// ---------------- K3 single-pass: bin via LDS cells + bump-cursor flush ----
// Replaces k1 + scan_a + scan_b + k3. Each (wg,bucket) stages <=CELL edges in
// an LDS cell; flush claims a 16-int-aligned base from gcursor[b] (one atomic
// per (wg,bucket)) and writes full 64B lines (edges + SENT pads). Cell
// overflow (P ~ 1e-5 per cell) spills one full line allocated directly.
__global__ __launch_bounds__(512) void k3_single(const int* __restrict__ src,
                                                 const int* __restrict__ dst,
                                                 int* __restrict__ gcursor,
                                                 int* __restrict__ packed,
                                                 int E, int chunk, int nbuck) {
    __shared__ int stage[NBK * CELL];
    __shared__ int lcell[NBK];
    __shared__ int gb[NBK];
    const int g = blockIdx.x;
    const int t = threadIdx.x;

    for (int i = t; i < nbuck; i += 512) lcell[i] = 0;
    __syncthreads();

    // phase 1: scatter this chunk's edges into per-bucket LDS cells
    const int e0 = g * chunk;
    const int e1 = min(E, e0 + chunk);
    for (int e = e0 + t; e < e1; e += 512) {
        const int d = dst[e];
        const int b = d >> BSHIFT;
        const int pk = ((d & (NPB - 1)) << 17) | src[e];
        const int pos = atomicAdd(&lcell[b], 1);
        if (pos < CELL) {
            stage[b * CELL + pos] = pk;
        } else {
            // rare spill: allocate one exclusive 64B line directly
            const int gpos = atomicAdd(&gcursor[b], 16);
            int* __restrict__ gp = packed + (size_t)b * CAP + gpos;
            gp[0] = pk;
#pragma unroll
            for (int j = 1; j < 16; ++j) gp[j] = SENT;
        }
    }
    __syncthreads();

    // phase 2a: claim flush bases (start offset per block decorrelates the
    // per-bucket atomic chains across blocks)
    for (int i = t; i < nbuck; i += 512) {
        const int bb = (i + g) % nbuck;
        const int cnt = min(lcell[bb], CELL);
        gb[bb] = (cnt > 0) ? atomicAdd(&gcursor[bb], (cnt + 15) & ~15) : 0;
    }
    __syncthreads();

    // phase 2b: full-line flush; 32 bucket-slots, 16 lanes each
    const int sub = t >> 4;
    const int l16 = t & 15;
    for (int b = sub; b < nbuck; b += 32) {
        const int cnt = min(lcell[b], CELL);   // uniform within 16-lane group
        if (cnt == 0) continue;
        const int n4 = ((cnt + 15) & ~15) >> 2;  // <= 12 int4s
        if (l16 < n4) {
            const int s0 = 4 * l16;
            int4 v;
            v.x = (s0 + 0 < cnt) ? stage[b * CELL + s0 + 0] : SENT;
            v.y = (s0 + 1 < cnt) ? stage[b * CELL + s0 + 1] : SENT;
            v.z = (s0 + 2 < cnt) ? stage[b * CELL + s0 + 2] : SENT;
            v.w = (s0 + 3 < cnt) ? stage[b * CELL + s0 + 3] : SENT;
            *(int4*)(packed + (size_t)b * CAP + gb[b] + s0) = v;
        }
    }
}

// ---------------- K4: within-bucket sort (LDS-staged, in-place, 512 thr) ----
__global__ __launch_bounds__(512) void k4_local_sort(const int* __restrict__ gcursor,
                                                     int* __restrict__ packed,
                                                     int* __restrict__ rowbeg,
                                                     int* __restrict__ rowend,
                                                     float* __restrict__ dinv,
                                                     int N, int nbuck) {
    __shared__ int sseg[SEGCAP];
    __shared__ int lcnt[NPB];
    __shared__ int s[NPB];
    __shared__ int lpos[NPB];
    const int b = blockIdx.x;
    const int segbeg = b * CAP;
    int seglen = gcursor[b];
    if (seglen > SEGCAP) seglen = SEGCAP;  // safety clamp (9-sigma margin)
    const int n0 = b << BSHIFT;
    const int ncnt = min(N - n0, NPB);
    const int t = threadIdx.x;

    if (t < NPB) lcnt[t] = 0;
    // coalesced load of the whole segment (incl. sentinels) into LDS
    for (int i = t; i < seglen; i += 512) sseg[i] = packed[segbeg + i];
    __syncthreads();
    for (int i = t; i < seglen; i += 512) {
        const int p = sseg[i];
        if (p >= 0) atomicAdd(&lcnt[(p >> 17) & (NPB - 1)], 1);
    }
    __syncthreads();
    // inclusive scan of lcnt into s (first NPB threads; barriers wave-uniform)
    if (t < NPB) s[t] = lcnt[t];
    __syncthreads();
    for (int off = 1; off < NPB; off <<= 1) {
        int v = 0;
        if (t < NPB && t >= off) v = s[t - off];
        __syncthreads();
        if (t < NPB) s[t] += v;
        __syncthreads();
    }
    if (t < NPB) {
        const int excl = s[t] - lcnt[t];
        lpos[t] = excl;
        if (t < ncnt) {
            rowbeg[n0 + t] = segbeg + excl;
            rowend[n0 + t] = segbeg + s[t];
            dinv[n0 + t] = rsqrtf((float)(lcnt[t] + 1));  // +1 self-loop
        }
    }
    __syncthreads();
    // scatter compact col values back into packed[] (reads all from LDS)
    for (int i = t; i < seglen; i += 512) {
        const int p = sseg[i];
        if (p >= 0) {
            const int dl = (p >> 17) & (NPB - 1);
            const int pos = segbeg + atomicAdd(&lpos[dl], 1);
            packed[pos] = p & 0x1FFFF;
        }
    }
}

// ---------------- h2 = bf16((x @ W) * dinv[row])  via bf16x3 MFMA ----------------
__global__ __launch_bounds__(512) void gemm_mfma_kernel(const float* __restrict__ x,
                                                        const float* __restrict__ W,
                                                        const float* __restrict__ dinv,
                                                        unsigned short* __restrict__ h2,
                                                        int N) {
    __shared__ unsigned short Whi[COUT * WPAD];
    __shared__ unsigned short Wlo[COUT * WPAD];
    for (int i = threadIdx.x; i < CIN * COUT; i += 512) {
        int k = i >> 6, c = i & 63;
        float w = W[i];
        unsigned u = fbits(w);
        unsigned short h = (unsigned short)(u >> 16);  // trunc split
        float r = w - bbits(u & 0xFFFF0000u);
        Whi[c * WPAD + k] = h;
        Wlo[c * WPAD + k] = (unsigned short)(fbits(r) >> 16);
    }
    __syncthreads();

    const int lane = threadIdx.x & 63;
    const int wave = threadIdx.x >> 6;
    const int m = lane & 15;
    const int q = lane >> 4;
    const int row0 = blockIdx.x * 256 + wave * 32;

    int ar0 = row0 + m;
    int ar1 = row0 + 16 + m;
    if (ar0 >= N) ar0 = N - 1;  // clamp; stores are guarded
    if (ar1 >= N) ar1 = N - 1;
    const float* __restrict__ xr0 = x + (size_t)ar0 * CIN + q * 8;
    const float* __restrict__ xr1 = x + (size_t)ar1 * CIN + q * 8;

    floatx4 acc0[4] = {floatx4{0,0,0,0}, floatx4{0,0,0,0}, floatx4{0,0,0,0}, floatx4{0,0,0,0}};
    floatx4 acc1[4] = {floatx4{0,0,0,0}, floatx4{0,0,0,0}, floatx4{0,0,0,0}, floatx4{0,0,0,0}};

#pragma unroll
    for (int kc = 0; kc < 8; ++kc) {
        floatx4 a00 = *(const floatx4*)(xr0 + kc * 32);
        floatx4 a01 = *(const floatx4*)(xr0 + kc * 32 + 4);
        floatx4 a10 = *(const floatx4*)(xr1 + kc * 32);
        floatx4 a11 = *(const floatx4*)(xr1 + kc * 32 + 4);
        short8 ahi0, alo0, ahi1, alo1;
        split8(a00, a01, ahi0, alo0);
        split8(a10, a11, ahi1, alo1);
        const int kb = kc * 32 + q * 8;
#pragma unroll
        for (int ct = 0; ct < 4; ++ct) {
            const int c = ct * 16 + m;
            short8 bhi = *(const short8*)&Whi[c * WPAD + kb];
            short8 blo = *(const short8*)&Wlo[c * WPAD + kb];
            acc0[ct] = __builtin_amdgcn_mfma_f32_16x16x32_bf16(ahi0, bhi, acc0[ct], 0, 0, 0);
            acc0[ct] = __builtin_amdgcn_mfma_f32_16x16x32_bf16(ahi0, blo, acc0[ct], 0, 0, 0);
            acc0[ct] = __builtin_amdgcn_mfma_f32_16x16x32_bf16(alo0, bhi, acc0[ct], 0, 0, 0);
            acc1[ct] = __builtin_amdgcn_mfma_f32_16x16x32_bf16(ahi1, bhi, acc1[ct], 0, 0, 0);
            acc1[ct] = __builtin_amdgcn_mfma_f32_16x16x32_bf16(ahi1, blo, acc1[ct], 0, 0, 0);
            acc1[ct] = __builtin_amdgcn_mfma_f32_16x16x32_bf16(alo1, bhi, acc1[ct], 0, 0, 0);
        }
    }

    // C/D layout: col = lane&15 (= m), row = q*4 + reg
#pragma unroll
    for (int t = 0; t < 2; ++t) {
#pragma unroll
        for (int r = 0; r < 4; ++r) {
            const int row = row0 + t * 16 + q * 4 + r;
            if (row < N) {
                const float dv = dinv[row];
                unsigned short* __restrict__ op = h2 + (size_t)row * COUT;
#pragma unroll
                for (int ct = 0; ct < 4; ++ct) {
                    float v = (t == 0) ? acc0[ct][r] : acc1[ct][r];
                    op[ct * 16 + m] = f2bf(v * dv);
                }
            }
        }
    }
}

// ---------------- pull-gather: one wave per node, lane = channel PAIR ----------------
// Proven R7 version: 16 edges/iter (8 h2 rows in flight per half) + col prefetch.
__global__ __launch_bounds__(256) void gather_kernel(const unsigned short* __restrict__ h2,
                                                     const int* __restrict__ rowbeg,
                                                     const int* __restrict__ rowend,
                                                     const int* __restrict__ col,
                                                     const float* __restrict__ dinv,
                                                     const float* __restrict__ b,
                                                     float* __restrict__ out, int N) {
    const int lane = threadIdx.x & 63;
    const int h = lane >> 5;
    const int c = lane & 31;
    const int node = blockIdx.x * 4 + (threadIdx.x >> 6);
    if (node >= N) return;
    const unsigned* __restrict__ h2u = (const unsigned*)h2;
    const int p0 = rowbeg[node];
    const int p1 = rowend[node];
    float a0 = 0.f, a1 = 0.f;
    int p = p0;

    const int nmain = (p1 - p0) >> 4;   // 16-edge iterations
    if (nmain > 0) {
        // preload col group 0 (8 edges per half)
        int e0 = col[p + h],      e1 = col[p + 2 + h];
        int e2 = col[p + 4 + h],  e3 = col[p + 6 + h];
        int e4 = col[p + 8 + h],  e5 = col[p + 10 + h];
        int e6 = col[p + 12 + h], e7 = col[p + 14 + h];
        for (int it = 0; it < nmain; ++it) {
            const unsigned u0 = h2u[(size_t)e0 * 32 + c];
            const unsigned u1 = h2u[(size_t)e1 * 32 + c];
            const unsigned u2 = h2u[(size_t)e2 * 32 + c];
            const unsigned u3 = h2u[(size_t)e3 * 32 + c];
            const unsigned u4 = h2u[(size_t)e4 * 32 + c];
            const unsigned u5 = h2u[(size_t)e5 * 32 + c];
            const unsigned u6 = h2u[(size_t)e6 * 32 + c];
            const unsigned u7 = h2u[(size_t)e7 * 32 + c];
            const int pn = p + 16;
            if (it + 1 < nmain) {  // prefetch next col group while h2 loads fly
                e0 = col[pn + h];      e1 = col[pn + 2 + h];
                e2 = col[pn + 4 + h];  e3 = col[pn + 6 + h];
                e4 = col[pn + 8 + h];  e5 = col[pn + 10 + h];
                e6 = col[pn + 12 + h]; e7 = col[pn + 14 + h];
            }
            a0 += ((bbits(u0 << 16) + bbits(u1 << 16)) + (bbits(u2 << 16) + bbits(u3 << 16))) +
                  ((bbits(u4 << 16) + bbits(u5 << 16)) + (bbits(u6 << 16) + bbits(u7 << 16)));
            a1 += ((bbits(u0 & 0xFFFF0000u) + bbits(u1 & 0xFFFF0000u)) +
                   (bbits(u2 & 0xFFFF0000u) + bbits(u3 & 0xFFFF0000u))) +
                  ((bbits(u4 & 0xFFFF0000u) + bbits(u5 & 0xFFFF0000u)) +
                   (bbits(u6 & 0xFFFF0000u) + bbits(u7 & 0xFFFF0000u)));
            p = pn;
        }
    }
    // 8-edge leftover (runs at most once)
    for (; p + 7 < p1; p += 8) {
        const int e0 = col[p + h],     e1 = col[p + 2 + h];
        const int e2 = col[p + 4 + h], e3 = col[p + 6 + h];
        const unsigned u0 = h2u[(size_t)e0 * 32 + c];
        const unsigned u1 = h2u[(size_t)e1 * 32 + c];
        const unsigned u2 = h2u[(size_t)e2 * 32 + c];
        const unsigned u3 = h2u[(size_t)e3 * 32 + c];
        a0 += (bbits(u0 << 16) + bbits(u1 << 16)) + (bbits(u2 << 16) + bbits(u3 << 16));
        a1 += (bbits(u0 & 0xFFFF0000u) + bbits(u1 & 0xFFFF0000u)) +
              (bbits(u2 & 0xFFFF0000u) + bbits(u3 & 0xFFFF0000u));
    }
    for (; p + 1 < p1; p += 2) {
        const int e = col[p + h];
        const unsigned u = h2u[(size_t)e * 32 + c];
        a0 += bbits(u << 16);
        a1 += bbits(u & 0xFFFF0000u);
    }
    if (p < p1 && h == 0) {  // odd leftover edge: half 0 only
        const unsigned u = h2u[(size_t)col[p] * 32 + c];
        a0 += bbits(u << 16);
        a1 += bbits(u & 0xFFFF0000u);
    }
    // combine edge-parity halves
    a0 += __shfl_xor(a0, 32, 64);
    a1 += __shfl_xor(a1, 32, 64);
    if (h == 0) {
        const unsigned su = h2u[(size_t)node * 32 + c];  // self-loop term
        const float dv = dinv[node];
        const float2 bb = ((const float2*)b)[c];
        float2 o;
        o.x = (a0 + bbits(su << 16)) * dv + bb.x;
        o.y = (a1 + bbits(su & 0xFFFF0000u)) * dv + bb.y;
        ((float2*)out)[(size_t)node * 32 + c] = o;
    }
}

// ---------------- launch ----------------
extern "C" void kernel_launch(void* const* d_in, const int* in_sizes, int n_in,
                              void* d_out, int out_size, void* d_ws, size_t ws_size,
                              hipStream_t stream) {
    const float* x = (const float*)d_in[0];
    const int* ei = (const int*)d_in[1];
    const float* W = (const float*)d_in[2];
    const float* b = (const float*)d_in[3];
    float* out = (float*)d_out;

    const int N = in_sizes[0] / CIN;
    const int E = in_sizes[1] / 2;
    const int* src = ei;
    const int* dst = ei + E;

    const int nbuck = (N + NPB - 1) >> BSHIFT;        // 391 (<= NBK)
    const int chunk = (E + NWG - 1) / NWG;             // 6250

    // workspace layout (256 B aligned chunks); total ~35 MB
    auto align_up = [](size_t v) { return (v + 255) & ~(size_t)255; };
    char* ws = (char*)d_ws;
    size_t off = 0;
    int* gcursor = (int*)(ws + off);  off = align_up(off + (size_t)nbuck * 4);
    int* rowbeg = (int*)(ws + off);   off = align_up(off + (size_t)N * 4);
    int* rowend = (int*)(ws + off);   off = align_up(off + (size_t)N * 4);
    float* dinv = (float*)(ws + off); off = align_up(off + (size_t)N * 4);
    int* packed = (int*)(ws + off);   off = align_up(off + (size_t)nbuck * CAP * 4);
    unsigned short* h2 = (unsigned short*)(ws + off);
    off = align_up(off + (size_t)N * COUT * 2);
    (void)ws_size;

    // 0. zero per-bucket bump cursors
    hipMemsetAsync(gcursor, 0, (size_t)nbuck * 4, stream);
    // 1. single-pass binned append (LDS cells + cursor-allocated full-line flush)
    k3_single<<<NWG, 512, 0, stream>>>(src, dst, gcursor, packed, E, chunk, nbuck);
    // 2. within-bucket counting sort, LDS-staged, in-place -> rowbeg/rowend, dinv
    k4_local_sort<<<nbuck, 512, 0, stream>>>(gcursor, packed, rowbeg, rowend, dinv, N, nbuck);
    // 3. projection h2 = bf16((x@W)*dinv) via bf16x3 MFMA, 32 rows/wave
    gemm_mfma_kernel<<<(N + 255) / 256, 512, 0, stream>>>(x, W, dinv, h2, N);
    // 4. pull-gather + bias (16-edge pipelined main loop, col prefetch; col==packed)
    gather_kernel<<<(N + 3) / 4, 256, 0, stream>>>(h2, rowbeg, rowend, packed, dinv, b, out, N);
}